// Round 1
// baseline (1472.856 us; speedup 1.0000x reference)
//
#include <hip/hip_runtime.h>
#include <hip/hip_bf16.h>
#include <math.h>

// Problem constants
#define BATCH 4
#define SEQ   1024
#define NTOK  4096          // BATCH*SEQ
#define DMODEL 768
#define DINNER 1536
#define E2     3072         // 2*DINNER
#define DTRANK 48
#define DSTATE 16
#define XPROJ_N 80          // DTRANK + 2*DSTATE

// ---------------------------------------------------------------------------
// Kernel 1: per-token rstd for RMSNorm.  One wave per token.
__global__ __launch_bounds__(256) void rstd_kernel(const float* __restrict__ x,
                                                   float* __restrict__ rstd) {
    int t    = blockIdx.x * 4 + (threadIdx.x >> 6);
    int lane = threadIdx.x & 63;
    const float4* xp = (const float4*)(x + (size_t)t * DMODEL);
    float ss = 0.f;
#pragma unroll
    for (int i = 0; i < 3; ++i) {            // 768 = 64 lanes * 3 * 4
        float4 v = xp[lane + 64 * i];
        ss += v.x * v.x + v.y * v.y + v.z * v.z + v.w * v.w;
    }
#pragma unroll
    for (int m = 32; m >= 1; m >>= 1) ss += __shfl_xor(ss, m, 64);
    if (lane == 0) rstd[t] = rsqrtf(ss * (1.f / DMODEL) + 1e-5f);
}

// ---------------------------------------------------------------------------
// Tiled fp32 GEMM, C[M,N] = A[M,K] * B[N,K]^T  (both row-major, K contiguous).
// 128x128 tile, BK=8, 256 threads, 8x8 micro-tile.
// RMSNORM: A element scaled by rms_w[k]*rstd[row].
// RESID:   C += resid (same layout as C).
template<int N, int K, bool RMSNORM, bool RESID>
__global__ __launch_bounds__(256) void gemm_nt(
    const float* __restrict__ A, const float* __restrict__ Bmat,
    float* __restrict__ C, const float* __restrict__ rms_w,
    const float* __restrict__ rstd, const float* __restrict__ resid) {
    __shared__ float As[8][132];
    __shared__ float Bs[8][132];
    const int tid  = threadIdx.x;
    const int row0 = blockIdx.y * 128;
    const int col0 = blockIdx.x * 128;
    const int lr = tid >> 1;            // 0..127 tile row for loads
    const int lk = (tid & 1) * 4;       // 0 or 4
    const int tx = tid & 15, ty = tid >> 4;

    float acc[8][8];
#pragma unroll
    for (int i = 0; i < 8; ++i)
#pragma unroll
        for (int j = 0; j < 8; ++j) acc[i][j] = 0.f;

    float rsv = 1.f;
    if (RMSNORM) rsv = rstd[row0 + lr];
    const float* ap = A    + (size_t)(row0 + lr) * K + lk;
    const float* bp = Bmat + (size_t)(col0 + lr) * K + lk;

    for (int k0 = 0; k0 < K; k0 += 8) {
        float4 av = *(const float4*)(ap + k0);
        if (RMSNORM) {
            float4 wv = *(const float4*)(rms_w + k0 + lk);
            av.x *= wv.x * rsv; av.y *= wv.y * rsv;
            av.z *= wv.z * rsv; av.w *= wv.w * rsv;
        }
        float4 bv = *(const float4*)(bp + k0);
        As[lk + 0][lr] = av.x; As[lk + 1][lr] = av.y;
        As[lk + 2][lr] = av.z; As[lk + 3][lr] = av.w;
        Bs[lk + 0][lr] = bv.x; Bs[lk + 1][lr] = bv.y;
        Bs[lk + 2][lr] = bv.z; Bs[lk + 3][lr] = bv.w;
        __syncthreads();
#pragma unroll
        for (int kk = 0; kk < 8; ++kk) {
            float4 a0 = *(const float4*)&As[kk][ty * 4];
            float4 a1 = *(const float4*)&As[kk][64 + ty * 4];
            float4 b0 = *(const float4*)&Bs[kk][tx * 4];
            float4 b1 = *(const float4*)&Bs[kk][64 + tx * 4];
            float am[8] = {a0.x, a0.y, a0.z, a0.w, a1.x, a1.y, a1.z, a1.w};
            float bn[8] = {b0.x, b0.y, b0.z, b0.w, b1.x, b1.y, b1.z, b1.w};
#pragma unroll
            for (int i = 0; i < 8; ++i)
#pragma unroll
                for (int j = 0; j < 8; ++j)
                    acc[i][j] = fmaf(am[i], bn[j], acc[i][j]);
        }
        __syncthreads();
    }

#pragma unroll
    for (int i = 0; i < 8; ++i) {
        int mrow = row0 + ((i < 4) ? (ty * 4 + i) : (64 + ty * 4 + i - 4));
        float* cp = C + (size_t)mrow * N + col0;
        float4 v0 = {acc[i][0], acc[i][1], acc[i][2], acc[i][3]};
        float4 v1 = {acc[i][4], acc[i][5], acc[i][6], acc[i][7]};
        if (RESID) {
            const float* rp = resid + (size_t)mrow * N + col0;
            float4 r0 = *(const float4*)(rp + tx * 4);
            float4 r1 = *(const float4*)(rp + 64 + tx * 4);
            v0.x += r0.x; v0.y += r0.y; v0.z += r0.z; v0.w += r0.w;
            v1.x += r1.x; v1.y += r1.y; v1.z += r1.z; v1.w += r1.w;
        }
        *(float4*)(cp + tx * 4)      = v0;
        *(float4*)(cp + 64 + tx * 4) = v1;
    }
}

// ---------------------------------------------------------------------------
// Kernel 3: causal depthwise conv (d_conv=4) + SiLU.   u = xz[:, :1536]
__global__ __launch_bounds__(256) void conv_silu_kernel(
    const float* __restrict__ xz, const float* __restrict__ conv_w,
    const float* __restrict__ conv_b, float* __restrict__ uc) {
    int idx = blockIdx.x * 256 + threadIdx.x;      // over NTOK*DINNER
    int c = idx % DINNER;
    int t = idx / DINNER;
    int l = t & (SEQ - 1);
    float4 w = *(const float4*)(conv_w + c * 4);
    float a = conv_b[c];
    const float* up = xz + (size_t)t * E2 + c;
    if (l >= 3) a = fmaf(up[-3 * E2], w.x, a);
    if (l >= 2) a = fmaf(up[-2 * E2], w.y, a);
    if (l >= 1) a = fmaf(up[-1 * E2], w.z, a);
    a = fmaf(up[0], w.w, a);
    uc[(size_t)t * DINNER + c] = a / (1.f + expf(-a));   // silu
}

// ---------------------------------------------------------------------------
// Kernel 4: fused x_proj (80 outputs per token) + dt projection + softplus.
// One block (256 threads = 4 waves) per token.
__global__ __launch_bounds__(256) void xproj_dt_kernel(
    const float* __restrict__ uc, const float* __restrict__ W_xproj,
    const float* __restrict__ W_dt, const float* __restrict__ b_dt,
    float* __restrict__ xdb, float* __restrict__ dtb) {
    int t = blockIdx.x;
    int tid = threadIdx.x;
    __shared__ float su[DINNER];
    __shared__ float sx[XPROJ_N];
    const float4* ur = (const float4*)(uc + (size_t)t * DINNER);
    float4* su4 = (float4*)su;
    su4[tid] = ur[tid];
    if (tid < DINNER / 4 - 256) su4[256 + tid] = ur[256 + tid];
    __syncthreads();

    int w = tid >> 6, lane = tid & 63;
    for (int jj = 0; jj < 20; ++jj) {          // 80 = 4 waves * 20
        int j = w * 20 + jj;
        const float* wr = W_xproj + (size_t)j * DINNER;
        float s = 0.f;
#pragma unroll
        for (int i = 0; i < 24; ++i)
            s = fmaf(su[lane + 64 * i], wr[lane + 64 * i], s);
#pragma unroll
        for (int m = 32; m >= 1; m >>= 1) s += __shfl_xor(s, m, 64);
        if (lane == 0) sx[j] = s;
    }
    __syncthreads();
    if (tid < XPROJ_N) xdb[(size_t)t * XPROJ_N + tid] = sx[tid];

    // dt = softplus(sx[0:48] . W_dt[c,:] + b_dt[c])
    for (int c = tid; c < DINNER; c += 256) {
        const float4* wd = (const float4*)(W_dt + (size_t)c * DTRANK);
        float s = b_dt[c];
#pragma unroll
        for (int r = 0; r < 12; ++r) {
            float4 wv = wd[r];
            s = fmaf(sx[r * 4 + 0], wv.x, s);
            s = fmaf(sx[r * 4 + 1], wv.y, s);
            s = fmaf(sx[r * 4 + 2], wv.z, s);
            s = fmaf(sx[r * 4 + 3], wv.w, s);
        }
        dtb[(size_t)t * DINNER + c] = (s > 20.f) ? s : log1pf(expf(s));
    }
}

// ---------------------------------------------------------------------------
// Kernel 5: selective scan.  16 lanes per channel (one per state).
// Writes gated y in-place over dtb.
__global__ __launch_bounds__(256) void scan_kernel(
    const float* __restrict__ uc, const float* __restrict__ xz,
    const float* __restrict__ xdb, const float* __restrict__ A_log,
    const float* __restrict__ D_param, float* __restrict__ dtb) {
    int b  = blockIdx.y;                 // 0..3
    int cg = blockIdx.x;                 // 0..95
    int s  = threadIdx.x & 15;
    int ci = threadIdx.x >> 4;           // 0..15
    int c  = cg * 16 + ci;
    float Acs = -expf(A_log[c * DSTATE + s]);
    float Dc  = D_param[c];
    float h = 0.f;
    size_t t = (size_t)b * SEQ;
    for (int l = 0; l < SEQ; ++l, ++t) {
        float dtv = dtb[t * DINNER + c];
        float uv  = uc[t * DINNER + c];
        float zv  = xz[t * E2 + DINNER + c];
        float Bv  = xdb[t * XPROJ_N + DTRANK + s];
        float Cv  = xdb[t * XPROJ_N + DTRANK + DSTATE + s];
        float dA  = expf(dtv * Acs);
        h = fmaf(dA, h, dtv * uv * Bv);
        float p = h * Cv;
        p += __shfl_xor(p, 1, 64);
        p += __shfl_xor(p, 2, 64);
        p += __shfl_xor(p, 4, 64);
        p += __shfl_xor(p, 8, 64);
        if (s == 0)
            dtb[t * DINNER + c] = (p + uv * Dc) * (zv / (1.f + expf(-zv)));
    }
}

// ---------------------------------------------------------------------------
extern "C" void kernel_launch(void* const* d_in, const int* in_sizes, int n_in,
                              void* d_out, int out_size, void* d_ws, size_t ws_size,
                              hipStream_t stream) {
    const float* x       = (const float*)d_in[0];
    const float* rms_w   = (const float*)d_in[1];
    const float* W_in    = (const float*)d_in[2];
    const float* conv_w  = (const float*)d_in[3];
    const float* conv_b  = (const float*)d_in[4];
    const float* W_xproj = (const float*)d_in[5];
    const float* W_dt    = (const float*)d_in[6];
    const float* b_dt    = (const float*)d_in[7];
    const float* A_log   = (const float*)d_in[8];
    const float* D_param = (const float*)d_in[9];
    const float* W_out   = (const float*)d_in[10];
    float* out = (float*)d_out;

    float* ws    = (float*)d_ws;
    float* rstdb = ws;                         // 4096
    float* xzb   = rstdb + 4096;               // NTOK*E2      = 12582912
    float* ucb   = xzb + (size_t)NTOK * E2;    // NTOK*DINNER  = 6291456
    float* xdbb  = ucb + (size_t)NTOK * DINNER;        // NTOK*80
    float* dtb   = xdbb + (size_t)NTOK * XPROJ_N;      // NTOK*DINNER

    rstd_kernel<<<NTOK / 4, 256, 0, stream>>>(x, rstdb);

    gemm_nt<E2, DMODEL, true, false>
        <<<dim3(E2 / 128, NTOK / 128), 256, 0, stream>>>(
            x, W_in, xzb, rms_w, rstdb, nullptr);

    conv_silu_kernel<<<(NTOK * DINNER) / 256, 256, 0, stream>>>(
        xzb, conv_w, conv_b, ucb);

    xproj_dt_kernel<<<NTOK, 256, 0, stream>>>(
        ucb, W_xproj, W_dt, b_dt, xdbb, dtb);

    scan_kernel<<<dim3(DINNER / 16, BATCH), 256, 0, stream>>>(
        ucb, xzb, xdbb, A_log, D_param, dtb);

    gemm_nt<DMODEL, DINNER, false, true>
        <<<dim3(DMODEL / 128, NTOK / 128), 256, 0, stream>>>(
            dtb, W_out, out, nullptr, nullptr, x);
}

// Round 2
// 768.611 us; speedup vs baseline: 1.9163x; 1.9163x over previous
//
#include <hip/hip_runtime.h>
#include <hip/hip_bf16.h>
#include <math.h>

// Problem constants
#define BATCH 4
#define SEQ   1024
#define NTOK  4096          // BATCH*SEQ
#define DMODEL 768
#define DINNER 1536
#define E2     3072         // 2*DINNER
#define DTRANK 48
#define DSTATE 16
#define XPROJ_N 80          // DTRANK + 2*DSTATE
#define NC 16               // time chunks for the scan
#define CL (SEQ / NC)       // 64 steps per chunk

// ---------------------------------------------------------------------------
// Kernel 1: per-token rstd for RMSNorm.  One wave per token.
__global__ __launch_bounds__(256) void rstd_kernel(const float* __restrict__ x,
                                                   float* __restrict__ rstd) {
    int t    = blockIdx.x * 4 + (threadIdx.x >> 6);
    int lane = threadIdx.x & 63;
    const float4* xp = (const float4*)(x + (size_t)t * DMODEL);
    float ss = 0.f;
#pragma unroll
    for (int i = 0; i < 3; ++i) {            // 768 = 64 lanes * 3 * 4
        float4 v = xp[lane + 64 * i];
        ss += v.x * v.x + v.y * v.y + v.z * v.z + v.w * v.w;
    }
#pragma unroll
    for (int m = 32; m >= 1; m >>= 1) ss += __shfl_xor(ss, m, 64);
    if (lane == 0) rstd[t] = rsqrtf(ss * (1.f / DMODEL) + 1e-5f);
}

// ---------------------------------------------------------------------------
// Tiled fp32 GEMM, C[M,N] = A[M,K] * B[N,K]^T  (both row-major, K contiguous).
// 128x128 tile, BK=8, 256 threads, 8x8 micro-tile.
template<int N, int K, bool RMSNORM, bool RESID>
__global__ __launch_bounds__(256) void gemm_nt(
    const float* __restrict__ A, const float* __restrict__ Bmat,
    float* __restrict__ C, const float* __restrict__ rms_w,
    const float* __restrict__ rstd, const float* __restrict__ resid) {
    __shared__ float As[8][132];
    __shared__ float Bs[8][132];
    const int tid  = threadIdx.x;
    const int row0 = blockIdx.y * 128;
    const int col0 = blockIdx.x * 128;
    const int lr = tid >> 1;            // 0..127 tile row for loads
    const int lk = (tid & 1) * 4;       // 0 or 4
    const int tx = tid & 15, ty = tid >> 4;

    float acc[8][8];
#pragma unroll
    for (int i = 0; i < 8; ++i)
#pragma unroll
        for (int j = 0; j < 8; ++j) acc[i][j] = 0.f;

    float rsv = 1.f;
    if (RMSNORM) rsv = rstd[row0 + lr];
    const float* ap = A    + (size_t)(row0 + lr) * K + lk;
    const float* bp = Bmat + (size_t)(col0 + lr) * K + lk;

    for (int k0 = 0; k0 < K; k0 += 8) {
        float4 av = *(const float4*)(ap + k0);
        if (RMSNORM) {
            float4 wv = *(const float4*)(rms_w + k0 + lk);
            av.x *= wv.x * rsv; av.y *= wv.y * rsv;
            av.z *= wv.z * rsv; av.w *= wv.w * rsv;
        }
        float4 bv = *(const float4*)(bp + k0);
        As[lk + 0][lr] = av.x; As[lk + 1][lr] = av.y;
        As[lk + 2][lr] = av.z; As[lk + 3][lr] = av.w;
        Bs[lk + 0][lr] = bv.x; Bs[lk + 1][lr] = bv.y;
        Bs[lk + 2][lr] = bv.z; Bs[lk + 3][lr] = bv.w;
        __syncthreads();
#pragma unroll
        for (int kk = 0; kk < 8; ++kk) {
            float4 a0 = *(const float4*)&As[kk][ty * 4];
            float4 a1 = *(const float4*)&As[kk][64 + ty * 4];
            float4 b0 = *(const float4*)&Bs[kk][tx * 4];
            float4 b1 = *(const float4*)&Bs[kk][64 + tx * 4];
            float am[8] = {a0.x, a0.y, a0.z, a0.w, a1.x, a1.y, a1.z, a1.w};
            float bn[8] = {b0.x, b0.y, b0.z, b0.w, b1.x, b1.y, b1.z, b1.w};
#pragma unroll
            for (int i = 0; i < 8; ++i)
#pragma unroll
                for (int j = 0; j < 8; ++j)
                    acc[i][j] = fmaf(am[i], bn[j], acc[i][j]);
        }
        __syncthreads();
    }

#pragma unroll
    for (int i = 0; i < 8; ++i) {
        int mrow = row0 + ((i < 4) ? (ty * 4 + i) : (64 + ty * 4 + i - 4));
        float* cp = C + (size_t)mrow * N + col0;
        float4 v0 = {acc[i][0], acc[i][1], acc[i][2], acc[i][3]};
        float4 v1 = {acc[i][4], acc[i][5], acc[i][6], acc[i][7]};
        if (RESID) {
            const float* rp = resid + (size_t)mrow * N + col0;
            float4 r0 = *(const float4*)(rp + tx * 4);
            float4 r1 = *(const float4*)(rp + 64 + tx * 4);
            v0.x += r0.x; v0.y += r0.y; v0.z += r0.z; v0.w += r0.w;
            v1.x += r1.x; v1.y += r1.y; v1.z += r1.z; v1.w += r1.w;
        }
        *(float4*)(cp + tx * 4)      = v0;
        *(float4*)(cp + 64 + tx * 4) = v1;
    }
}

// ---------------------------------------------------------------------------
// Kernel 3: causal depthwise conv (d_conv=4) + SiLU.   u = xz[:, :1536]
__global__ __launch_bounds__(256) void conv_silu_kernel(
    const float* __restrict__ xz, const float* __restrict__ conv_w,
    const float* __restrict__ conv_b, float* __restrict__ uc) {
    int idx = blockIdx.x * 256 + threadIdx.x;      // over NTOK*DINNER
    int c = idx % DINNER;
    int t = idx / DINNER;
    int l = t & (SEQ - 1);
    float4 w = *(const float4*)(conv_w + c * 4);
    float a = conv_b[c];
    const float* up = xz + (size_t)t * E2 + c;
    if (l >= 3) a = fmaf(up[-3 * E2], w.x, a);
    if (l >= 2) a = fmaf(up[-2 * E2], w.y, a);
    if (l >= 1) a = fmaf(up[-1 * E2], w.z, a);
    a = fmaf(up[0], w.w, a);
    uc[(size_t)t * DINNER + c] = a / (1.f + expf(-a));   // silu
}

// ---------------------------------------------------------------------------
// Kernel 4: fused x_proj (80 outputs per token) + dt projection + softplus.
__global__ __launch_bounds__(256) void xproj_dt_kernel(
    const float* __restrict__ uc, const float* __restrict__ W_xproj,
    const float* __restrict__ W_dt, const float* __restrict__ b_dt,
    float* __restrict__ xdb, float* __restrict__ dtb) {
    int t = blockIdx.x;
    int tid = threadIdx.x;
    __shared__ float su[DINNER];
    __shared__ float sx[XPROJ_N];
    const float4* ur = (const float4*)(uc + (size_t)t * DINNER);
    float4* su4 = (float4*)su;
    su4[tid] = ur[tid];
    if (tid < DINNER / 4 - 256) su4[256 + tid] = ur[256 + tid];
    __syncthreads();

    int w = tid >> 6, lane = tid & 63;
    for (int jj = 0; jj < 20; ++jj) {          // 80 = 4 waves * 20
        int j = w * 20 + jj;
        const float* wr = W_xproj + (size_t)j * DINNER;
        float s = 0.f;
#pragma unroll
        for (int i = 0; i < 24; ++i)
            s = fmaf(su[lane + 64 * i], wr[lane + 64 * i], s);
#pragma unroll
        for (int m = 32; m >= 1; m >>= 1) s += __shfl_xor(s, m, 64);
        if (lane == 0) sx[j] = s;
    }
    __syncthreads();
    if (tid < XPROJ_N) xdb[(size_t)t * XPROJ_N + tid] = sx[tid];

    // dt = softplus(sx[0:48] . W_dt[c,:] + b_dt[c])
    for (int c = tid; c < DINNER; c += 256) {
        const float4* wd = (const float4*)(W_dt + (size_t)c * DTRANK);
        float s = b_dt[c];
#pragma unroll
        for (int r = 0; r < 12; ++r) {
            float4 wv = wd[r];
            s = fmaf(sx[r * 4 + 0], wv.x, s);
            s = fmaf(sx[r * 4 + 1], wv.y, s);
            s = fmaf(sx[r * 4 + 2], wv.z, s);
            s = fmaf(sx[r * 4 + 3], wv.w, s);
        }
        dtb[(size_t)t * DINNER + c] = (s > 20.f) ? s : log1pf(expf(s));
    }
}

// ---------------------------------------------------------------------------
// Selective scan, chunked two-pass.  Thread-per-channel, h[16] in registers.
// Pass 1: per (b,chunk,c) compute P = prod(dA) and S = chunk scan from h=0.
__global__ __launch_bounds__(256) void scan_pass1(
    const float* __restrict__ dtb, const float* __restrict__ ucb,
    const float* __restrict__ xdb, const float* __restrict__ A_log,
    float* __restrict__ Pbuf, float* __restrict__ Sbuf) {
    const int b = blockIdx.z, k = blockIdx.y, cb = blockIdx.x;
    const int tid = threadIdx.x;
    const int c = cb * 256 + tid;
    const int t0 = b * SEQ + k * CL;
    __shared__ float sB[CL][DSTATE];
    for (int i = tid; i < CL * DSTATE; i += 256) {
        int l = i >> 4, s = i & 15;
        sB[l][s] = xdb[(size_t)(t0 + l) * XPROJ_N + DTRANK + s];
    }
    __syncthreads();
    float Acs[DSTATE], h[DSTATE], P[DSTATE];
    const float4* al = (const float4*)(A_log + (size_t)c * DSTATE);
#pragma unroll
    for (int r = 0; r < 4; ++r) {
        float4 v = al[r];
        Acs[4*r+0] = -__expf(v.x); Acs[4*r+1] = -__expf(v.y);
        Acs[4*r+2] = -__expf(v.z); Acs[4*r+3] = -__expf(v.w);
    }
#pragma unroll
    for (int s = 0; s < DSTATE; ++s) { h[s] = 0.f; P[s] = 1.f; }

    size_t t = (size_t)t0;
    for (int l = 0; l < CL; ++l, ++t) {
        float dtv = dtb[t * DINNER + c];
        float uv  = ucb[t * DINNER + c];
        float Bv[DSTATE];
        *(float4*)&Bv[0]  = *(const float4*)&sB[l][0];
        *(float4*)&Bv[4]  = *(const float4*)&sB[l][4];
        *(float4*)&Bv[8]  = *(const float4*)&sB[l][8];
        *(float4*)&Bv[12] = *(const float4*)&sB[l][12];
        float dtu = dtv * uv;
#pragma unroll
        for (int s = 0; s < DSTATE; ++s) {
            float dA = __expf(dtv * Acs[s]);
            h[s] = fmaf(dA, h[s], dtu * Bv[s]);
            P[s] *= dA;
        }
    }
    size_t base = ((size_t)(b * NC + k) * DINNER + c) * DSTATE;
    float4* Pp = (float4*)(Pbuf + base);
    float4* Sp = (float4*)(Sbuf + base);
#pragma unroll
    for (int r = 0; r < 4; ++r) {
        Pp[r] = make_float4(P[4*r], P[4*r+1], P[4*r+2], P[4*r+3]);
        Sp[r] = make_float4(h[4*r], h[4*r+1], h[4*r+2], h[4*r+3]);
    }
}

// Pass 2: combine prior chunk summaries in-register, replay chunk, emit gated y.
// Writes y in-place over dtb (manual prefetch keeps loads ahead of the store).
__global__ __launch_bounds__(256) void scan_pass2(
    float* __restrict__ dtb, const float* __restrict__ ucb,
    const float* __restrict__ xz, const float* __restrict__ xdb,
    const float* __restrict__ A_log, const float* __restrict__ D_param,
    const float* __restrict__ Pbuf, const float* __restrict__ Sbuf) {
    const int b = blockIdx.z, k = blockIdx.y, cb = blockIdx.x;
    const int tid = threadIdx.x;
    const int c = cb * 256 + tid;
    const int t0 = b * SEQ + k * CL;
    __shared__ float sBC[CL][2 * DSTATE];
    for (int i = tid; i < CL * 2 * DSTATE; i += 256) {
        int l = i >> 5, j = i & 31;
        sBC[l][j] = xdb[(size_t)(t0 + l) * XPROJ_N + DTRANK + j];
    }
    __syncthreads();
    float Acs[DSTATE], h[DSTATE];
    const float4* al = (const float4*)(A_log + (size_t)c * DSTATE);
#pragma unroll
    for (int r = 0; r < 4; ++r) {
        float4 v = al[r];
        Acs[4*r+0] = -__expf(v.x); Acs[4*r+1] = -__expf(v.y);
        Acs[4*r+2] = -__expf(v.z); Acs[4*r+3] = -__expf(v.w);
    }
#pragma unroll
    for (int s = 0; s < DSTATE; ++s) h[s] = 0.f;
    for (int kk = 0; kk < k; ++kk) {
        size_t sb = ((size_t)(b * NC + kk) * DINNER + c) * DSTATE;
        const float4* Pp = (const float4*)(Pbuf + sb);
        const float4* Sp = (const float4*)(Sbuf + sb);
#pragma unroll
        for (int r = 0; r < 4; ++r) {
            float4 P4 = Pp[r]; float4 S4 = Sp[r];
            h[4*r+0] = fmaf(P4.x, h[4*r+0], S4.x);
            h[4*r+1] = fmaf(P4.y, h[4*r+1], S4.y);
            h[4*r+2] = fmaf(P4.z, h[4*r+2], S4.z);
            h[4*r+3] = fmaf(P4.w, h[4*r+3], S4.w);
        }
    }
    const float Dc = D_param[c];
    size_t t = (size_t)t0;
    float dtv = dtb[t * DINNER + c];
    float uv  = ucb[t * DINNER + c];
    float zv  = xz[t * E2 + DINNER + c];
    for (int l = 0; l < CL; ++l, ++t) {
        float dtn = 0.f, un = 0.f, zn = 0.f;
        if (l + 1 < CL) {                       // prefetch next step
            dtn = dtb[(t + 1) * DINNER + c];
            un  = ucb[(t + 1) * DINNER + c];
            zn  = xz[(t + 1) * E2 + DINNER + c];
        }
        float Bv[DSTATE], Cv[DSTATE];
        *(float4*)&Bv[0]  = *(const float4*)&sBC[l][0];
        *(float4*)&Bv[4]  = *(const float4*)&sBC[l][4];
        *(float4*)&Bv[8]  = *(const float4*)&sBC[l][8];
        *(float4*)&Bv[12] = *(const float4*)&sBC[l][12];
        *(float4*)&Cv[0]  = *(const float4*)&sBC[l][16];
        *(float4*)&Cv[4]  = *(const float4*)&sBC[l][20];
        *(float4*)&Cv[8]  = *(const float4*)&sBC[l][24];
        *(float4*)&Cv[12] = *(const float4*)&sBC[l][28];
        float dtu = dtv * uv;
        float y = 0.f;
#pragma unroll
        for (int s = 0; s < DSTATE; ++s) {
            float dA = __expf(dtv * Acs[s]);
            h[s] = fmaf(dA, h[s], dtu * Bv[s]);
            y = fmaf(h[s], Cv[s], y);
        }
        y = fmaf(uv, Dc, y);
        y *= zv / (1.f + __expf(-zv));
        dtb[t * DINNER + c] = y;
        dtv = dtn; uv = un; zv = zn;
    }
}

// ---------------------------------------------------------------------------
extern "C" void kernel_launch(void* const* d_in, const int* in_sizes, int n_in,
                              void* d_out, int out_size, void* d_ws, size_t ws_size,
                              hipStream_t stream) {
    const float* x       = (const float*)d_in[0];
    const float* rms_w   = (const float*)d_in[1];
    const float* W_in    = (const float*)d_in[2];
    const float* conv_w  = (const float*)d_in[3];
    const float* conv_b  = (const float*)d_in[4];
    const float* W_xproj = (const float*)d_in[5];
    const float* W_dt    = (const float*)d_in[6];
    const float* b_dt    = (const float*)d_in[7];
    const float* A_log   = (const float*)d_in[8];
    const float* D_param = (const float*)d_in[9];
    const float* W_out   = (const float*)d_in[10];
    float* out = (float*)d_out;

    float* ws    = (float*)d_ws;
    float* rstdb = ws;                                   // 4096
    float* xzb   = rstdb + 4096;                         // NTOK*E2
    float* ucb   = xzb + (size_t)NTOK * E2;              // NTOK*DINNER
    float* xdbb  = ucb + (size_t)NTOK * DINNER;          // NTOK*80
    float* dtb   = xdbb + (size_t)NTOK * XPROJ_N;        // NTOK*DINNER
    float* Pbuf  = dtb + (size_t)NTOK * DINNER;          // B*NC*DINNER*DSTATE
    float* Sbuf  = Pbuf + (size_t)BATCH * NC * DINNER * DSTATE;

    rstd_kernel<<<NTOK / 4, 256, 0, stream>>>(x, rstdb);

    gemm_nt<E2, DMODEL, true, false>
        <<<dim3(E2 / 128, NTOK / 128), 256, 0, stream>>>(
            x, W_in, xzb, rms_w, rstdb, nullptr);

    conv_silu_kernel<<<(NTOK * DINNER) / 256, 256, 0, stream>>>(
        xzb, conv_w, conv_b, ucb);

    xproj_dt_kernel<<<NTOK, 256, 0, stream>>>(
        ucb, W_xproj, W_dt, b_dt, xdbb, dtb);

    scan_pass1<<<dim3(DINNER / 256, NC - 1, BATCH), 256, 0, stream>>>(
        dtb, ucb, xdbb, A_log, Pbuf, Sbuf);

    scan_pass2<<<dim3(DINNER / 256, NC, BATCH), 256, 0, stream>>>(
        dtb, ucb, xzb, xdbb, A_log, D_param, Pbuf, Sbuf);

    gemm_nt<DMODEL, DINNER, false, true>
        <<<dim3(DMODEL / 128, NTOK / 128), 256, 0, stream>>>(
            dtb, W_out, out, nullptr, nullptr, x);
}

// Round 3
// 406.925 us; speedup vs baseline: 3.6195x; 1.8888x over previous
//
#include <hip/hip_runtime.h>
#include <hip/hip_bf16.h>
#include <math.h>

// Problem constants
#define BATCH 4
#define SEQ   1024
#define NTOK  4096          // BATCH*SEQ
#define DMODEL 768
#define DINNER 1536
#define E2     3072         // 2*DINNER
#define DTRANK 48
#define DSTATE 16
#define XPROJ_N 80          // DTRANK + 2*DSTATE
#define NC 16               // time chunks for the scan
#define CL (SEQ / NC)       // 64 steps per chunk

typedef __attribute__((ext_vector_type(8))) short bf16x8;
typedef __attribute__((ext_vector_type(4))) float f32x4;

__device__ __forceinline__ ushort f2bf(float f) {
    union { float f; unsigned u; } v; v.f = f;
    unsigned r = (v.u + 0x7FFF + ((v.u >> 16) & 1)) >> 16;   // RNE
    return (ushort)r;
}

// ---------------------------------------------------------------------------
// Kernel 1: fused RMSNorm -> bf16 xn.  One wave per token.
__global__ __launch_bounds__(256) void rmsnorm_bf16_kernel(
    const float* __restrict__ x, const float* __restrict__ rms_w,
    ushort* __restrict__ xnb) {
    int t    = blockIdx.x * 4 + (threadIdx.x >> 6);
    int lane = threadIdx.x & 63;
    const float4* xp = (const float4*)(x + (size_t)t * DMODEL);
    const float4* wp = (const float4*)rms_w;
    float4 v[3];
    float ss = 0.f;
#pragma unroll
    for (int i = 0; i < 3; ++i) {
        v[i] = xp[lane + 64 * i];
        ss += v[i].x * v[i].x + v[i].y * v[i].y + v[i].z * v[i].z + v[i].w * v[i].w;
    }
#pragma unroll
    for (int m = 32; m >= 1; m >>= 1) ss += __shfl_xor(ss, m, 64);
    float r = rsqrtf(ss * (1.f / DMODEL) + 1e-5f);
#pragma unroll
    for (int i = 0; i < 3; ++i) {
        float4 wv = wp[lane + 64 * i];
        ushort4 o = make_ushort4(f2bf(v[i].x * wv.x * r), f2bf(v[i].y * wv.y * r),
                                 f2bf(v[i].z * wv.z * r), f2bf(v[i].w * wv.w * r));
        *(ushort4*)(xnb + (size_t)t * DMODEL + (size_t)(lane + 64 * i) * 4) = o;
    }
}

// ---------------------------------------------------------------------------
// fp32 -> bf16 elementwise convert (for weights), float4 granularity.
__global__ __launch_bounds__(256) void f32_to_bf16_kernel(
    const float* __restrict__ in, ushort* __restrict__ out, int n4) {
    int i = blockIdx.x * 256 + threadIdx.x;
    if (i < n4) {
        float4 v = ((const float4*)in)[i];
        ((ushort4*)out)[i] = make_ushort4(f2bf(v.x), f2bf(v.y), f2bf(v.z), f2bf(v.w));
    }
}

// ---------------------------------------------------------------------------
// bf16 MFMA GEMM (m97 structure): C[M,N] = A[M,K] * B[N,K]^T (+ resid)
// A,B bf16 row-major K-contiguous; C fp32. 128x128 tile, BK=32, 256 threads.
// 4 waves in 2x2, each wave 64x64 = 4x4 fragments of 16x16x32 MFMA.
template<int N, int K, bool RESID>
__global__ __launch_bounds__(256) void gemm_bf16(
    const ushort* __restrict__ A, const ushort* __restrict__ B,
    float* __restrict__ C, const float* __restrict__ resid) {
    __shared__ ushort As[128 * 32];
    __shared__ ushort Bs[128 * 32];
    const int tid  = threadIdx.x;
    const int w    = tid >> 6, lane = tid & 63;
    const int row0 = blockIdx.y * 128, col0 = blockIdx.x * 128;
    const int wr   = (w >> 1) * 64, wc = (w & 1) * 64;

    f32x4 acc[4][4];
#pragma unroll
    for (int mi = 0; mi < 4; ++mi)
#pragma unroll
        for (int ni = 0; ni < 4; ++ni)
            acc[mi][ni] = (f32x4){0.f, 0.f, 0.f, 0.f};

    // staging: chunk ci covers LDS bf16 elements [ci*8, ci*8+8) of the linear
    // [128][32] tile; ci = (j*4 + w)*64 + lane, j = 0,1.  row=ci>>2, k=(ci&3)*8
    const int ci0 = w * 64 + lane;
    const int ci1 = 256 + w * 64 + lane;
    const ushort* ga0 = A + (size_t)(row0 + (ci0 >> 2)) * K + (ci0 & 3) * 8;
    const ushort* ga1 = A + (size_t)(row0 + (ci1 >> 2)) * K + (ci1 & 3) * 8;
    const ushort* gb0 = B + (size_t)(col0 + (ci0 >> 2)) * K + (ci0 & 3) * 8;
    const ushort* gb1 = B + (size_t)(col0 + (ci1 >> 2)) * K + (ci1 & 3) * 8;
    ushort* lda0 = As + w * 512;            // wave-uniform LDS bases
    ushort* lda1 = As + 2048 + w * 512;
    ushort* ldb0 = Bs + w * 512;
    ushort* ldb1 = Bs + 2048 + w * 512;

    const int fra = (lane & 15) * 32 + (lane >> 4) * 8;   // frag base (row part added per mi)

    for (int k0 = 0; k0 < K; k0 += 32) {
        __builtin_amdgcn_global_load_lds(
            (const __attribute__((address_space(1))) void*)(ga0 + k0),
            (__attribute__((address_space(3))) void*)lda0, 16, 0, 0);
        __builtin_amdgcn_global_load_lds(
            (const __attribute__((address_space(1))) void*)(ga1 + k0),
            (__attribute__((address_space(3))) void*)lda1, 16, 0, 0);
        __builtin_amdgcn_global_load_lds(
            (const __attribute__((address_space(1))) void*)(gb0 + k0),
            (__attribute__((address_space(3))) void*)ldb0, 16, 0, 0);
        __builtin_amdgcn_global_load_lds(
            (const __attribute__((address_space(1))) void*)(gb1 + k0),
            (__attribute__((address_space(3))) void*)ldb1, 16, 0, 0);
        __syncthreads();

        bf16x8 af[4], bfr[4];
#pragma unroll
        for (int mi = 0; mi < 4; ++mi)
            af[mi] = *(const bf16x8*)&As[(wr + mi * 16) * 32 + fra];
#pragma unroll
        for (int ni = 0; ni < 4; ++ni)
            bfr[ni] = *(const bf16x8*)&Bs[(wc + ni * 16) * 32 + fra];
#pragma unroll
        for (int mi = 0; mi < 4; ++mi)
#pragma unroll
            for (int ni = 0; ni < 4; ++ni)
                acc[mi][ni] = __builtin_amdgcn_mfma_f32_16x16x32_bf16(
                    af[mi], bfr[ni], acc[mi][ni], 0, 0, 0);
        __syncthreads();
    }

    // C/D layout: col = lane&15, row = (lane>>4)*4 + j
#pragma unroll
    for (int mi = 0; mi < 4; ++mi)
#pragma unroll
        for (int j = 0; j < 4; ++j) {
            int row = row0 + wr + mi * 16 + (lane >> 4) * 4 + j;
            float* cp = C + (size_t)row * N + col0 + wc + (lane & 15);
            const float* rp = RESID ? resid + (size_t)row * N + col0 + wc + (lane & 15)
                                    : nullptr;
#pragma unroll
            for (int ni = 0; ni < 4; ++ni) {
                float vv = acc[mi][ni][j];
                if (RESID) vv += rp[ni * 16];
                cp[ni * 16] = vv;
            }
        }
}

// ---------------------------------------------------------------------------
// Kernel 3: causal depthwise conv (d_conv=4) + SiLU.   u = xz[:, :1536]
__global__ __launch_bounds__(256) void conv_silu_kernel(
    const float* __restrict__ xz, const float* __restrict__ conv_w,
    const float* __restrict__ conv_b, float* __restrict__ uc) {
    int idx = blockIdx.x * 256 + threadIdx.x;      // over NTOK*DINNER
    int c = idx % DINNER;
    int t = idx / DINNER;
    int l = t & (SEQ - 1);
    float4 w = *(const float4*)(conv_w + c * 4);
    float a = conv_b[c];
    const float* up = xz + (size_t)t * E2 + c;
    if (l >= 3) a = fmaf(up[-3 * E2], w.x, a);
    if (l >= 2) a = fmaf(up[-2 * E2], w.y, a);
    if (l >= 1) a = fmaf(up[-1 * E2], w.z, a);
    a = fmaf(up[0], w.w, a);
    uc[(size_t)t * DINNER + c] = a / (1.f + __expf(-a));   // silu
}

// ---------------------------------------------------------------------------
// Kernel 4: fused x_proj (80 outputs per token) + dt projection + softplus.
__global__ __launch_bounds__(256) void xproj_dt_kernel(
    const float* __restrict__ uc, const float* __restrict__ W_xproj,
    const float* __restrict__ W_dt, const float* __restrict__ b_dt,
    float* __restrict__ xdb, float* __restrict__ dtb) {
    int t = blockIdx.x;
    int tid = threadIdx.x;
    __shared__ float su[DINNER];
    __shared__ float sx[XPROJ_N];
    const float4* ur = (const float4*)(uc + (size_t)t * DINNER);
    float4* su4 = (float4*)su;
    su4[tid] = ur[tid];
    if (tid < DINNER / 4 - 256) su4[256 + tid] = ur[256 + tid];
    __syncthreads();

    int w = tid >> 6, lane = tid & 63;
    for (int jj = 0; jj < 20; ++jj) {          // 80 = 4 waves * 20
        int j = w * 20 + jj;
        const float* wr = W_xproj + (size_t)j * DINNER;
        float s = 0.f;
#pragma unroll
        for (int i = 0; i < 24; ++i)
            s = fmaf(su[lane + 64 * i], wr[lane + 64 * i], s);
#pragma unroll
        for (int m = 32; m >= 1; m >>= 1) s += __shfl_xor(s, m, 64);
        if (lane == 0) sx[j] = s;
    }
    __syncthreads();
    if (tid < XPROJ_N) xdb[(size_t)t * XPROJ_N + tid] = sx[tid];

    // dt = softplus(sx[0:48] . W_dt[c,:] + b_dt[c])
    for (int c = tid; c < DINNER; c += 256) {
        const float4* wd = (const float4*)(W_dt + (size_t)c * DTRANK);
        float s = b_dt[c];
#pragma unroll
        for (int r = 0; r < 12; ++r) {
            float4 wv = wd[r];
            s = fmaf(sx[r * 4 + 0], wv.x, s);
            s = fmaf(sx[r * 4 + 1], wv.y, s);
            s = fmaf(sx[r * 4 + 2], wv.z, s);
            s = fmaf(sx[r * 4 + 3], wv.w, s);
        }
        dtb[(size_t)t * DINNER + c] = (s > 20.f) ? s : log1pf(__expf(s));
    }
}

// ---------------------------------------------------------------------------
// Selective scan, chunked two-pass.  Thread-per-channel, h[16] in registers.
__global__ __launch_bounds__(256) void scan_pass1(
    const float* __restrict__ dtb, const float* __restrict__ ucb,
    const float* __restrict__ xdb, const float* __restrict__ A_log,
    float* __restrict__ Pbuf, float* __restrict__ Sbuf) {
    const int b = blockIdx.z, k = blockIdx.y, cb = blockIdx.x;
    const int tid = threadIdx.x;
    const int c = cb * 256 + tid;
    const int t0 = b * SEQ + k * CL;
    __shared__ float sB[CL][DSTATE];
    for (int i = tid; i < CL * DSTATE; i += 256) {
        int l = i >> 4, s = i & 15;
        sB[l][s] = xdb[(size_t)(t0 + l) * XPROJ_N + DTRANK + s];
    }
    __syncthreads();
    float Acs[DSTATE], h[DSTATE], P[DSTATE];
    const float4* al = (const float4*)(A_log + (size_t)c * DSTATE);
#pragma unroll
    for (int r = 0; r < 4; ++r) {
        float4 v = al[r];
        Acs[4*r+0] = -__expf(v.x); Acs[4*r+1] = -__expf(v.y);
        Acs[4*r+2] = -__expf(v.z); Acs[4*r+3] = -__expf(v.w);
    }
#pragma unroll
    for (int s = 0; s < DSTATE; ++s) { h[s] = 0.f; P[s] = 1.f; }

    size_t t = (size_t)t0;
    for (int l = 0; l < CL; ++l, ++t) {
        float dtv = dtb[t * DINNER + c];
        float uv  = ucb[t * DINNER + c];
        float Bv[DSTATE];
        *(float4*)&Bv[0]  = *(const float4*)&sB[l][0];
        *(float4*)&Bv[4]  = *(const float4*)&sB[l][4];
        *(float4*)&Bv[8]  = *(const float4*)&sB[l][8];
        *(float4*)&Bv[12] = *(const float4*)&sB[l][12];
        float dtu = dtv * uv;
#pragma unroll
        for (int s = 0; s < DSTATE; ++s) {
            float dA = __expf(dtv * Acs[s]);
            h[s] = fmaf(dA, h[s], dtu * Bv[s]);
            P[s] *= dA;
        }
    }
    size_t base = ((size_t)(b * NC + k) * DINNER + c) * DSTATE;
    float4* Pp = (float4*)(Pbuf + base);
    float4* Sp = (float4*)(Sbuf + base);
#pragma unroll
    for (int r = 0; r < 4; ++r) {
        Pp[r] = make_float4(P[4*r], P[4*r+1], P[4*r+2], P[4*r+3]);
        Sp[r] = make_float4(h[4*r], h[4*r+1], h[4*r+2], h[4*r+3]);
    }
}

// Pass 2: combine prior chunk summaries in-register, replay chunk, emit gated y
// directly in bf16 (GEMM3's A operand).
__global__ __launch_bounds__(256) void scan_pass2(
    const float* __restrict__ dtb, const float* __restrict__ ucb,
    const float* __restrict__ xz, const float* __restrict__ xdb,
    const float* __restrict__ A_log, const float* __restrict__ D_param,
    const float* __restrict__ Pbuf, const float* __restrict__ Sbuf,
    ushort* __restrict__ ybf) {
    const int b = blockIdx.z, k = blockIdx.y, cb = blockIdx.x;
    const int tid = threadIdx.x;
    const int c = cb * 256 + tid;
    const int t0 = b * SEQ + k * CL;
    __shared__ float sBC[CL][2 * DSTATE];
    for (int i = tid; i < CL * 2 * DSTATE; i += 256) {
        int l = i >> 5, j = i & 31;
        sBC[l][j] = xdb[(size_t)(t0 + l) * XPROJ_N + DTRANK + j];
    }
    __syncthreads();
    float Acs[DSTATE], h[DSTATE];
    const float4* al = (const float4*)(A_log + (size_t)c * DSTATE);
#pragma unroll
    for (int r = 0; r < 4; ++r) {
        float4 v = al[r];
        Acs[4*r+0] = -__expf(v.x); Acs[4*r+1] = -__expf(v.y);
        Acs[4*r+2] = -__expf(v.z); Acs[4*r+3] = -__expf(v.w);
    }
#pragma unroll
    for (int s = 0; s < DSTATE; ++s) h[s] = 0.f;
    for (int kk = 0; kk < k; ++kk) {
        size_t sb = ((size_t)(b * NC + kk) * DINNER + c) * DSTATE;
        const float4* Pp = (const float4*)(Pbuf + sb);
        const float4* Sp = (const float4*)(Sbuf + sb);
#pragma unroll
        for (int r = 0; r < 4; ++r) {
            float4 P4 = Pp[r]; float4 S4 = Sp[r];
            h[4*r+0] = fmaf(P4.x, h[4*r+0], S4.x);
            h[4*r+1] = fmaf(P4.y, h[4*r+1], S4.y);
            h[4*r+2] = fmaf(P4.z, h[4*r+2], S4.z);
            h[4*r+3] = fmaf(P4.w, h[4*r+3], S4.w);
        }
    }
    const float Dc = D_param[c];
    size_t t = (size_t)t0;
    float dtv = dtb[t * DINNER + c];
    float uv  = ucb[t * DINNER + c];
    float zv  = xz[t * E2 + DINNER + c];
    for (int l = 0; l < CL; ++l, ++t) {
        float dtn = 0.f, un = 0.f, zn = 0.f;
        if (l + 1 < CL) {                       // prefetch next step
            dtn = dtb[(t + 1) * DINNER + c];
            un  = ucb[(t + 1) * DINNER + c];
            zn  = xz[(t + 1) * E2 + DINNER + c];
        }
        float Bv[DSTATE], Cv[DSTATE];
        *(float4*)&Bv[0]  = *(const float4*)&sBC[l][0];
        *(float4*)&Bv[4]  = *(const float4*)&sBC[l][4];
        *(float4*)&Bv[8]  = *(const float4*)&sBC[l][8];
        *(float4*)&Bv[12] = *(const float4*)&sBC[l][12];
        *(float4*)&Cv[0]  = *(const float4*)&sBC[l][16];
        *(float4*)&Cv[4]  = *(const float4*)&sBC[l][20];
        *(float4*)&Cv[8]  = *(const float4*)&sBC[l][24];
        *(float4*)&Cv[12] = *(const float4*)&sBC[l][28];
        float dtu = dtv * uv;
        float y = 0.f;
#pragma unroll
        for (int s = 0; s < DSTATE; ++s) {
            float dA = __expf(dtv * Acs[s]);
            h[s] = fmaf(dA, h[s], dtu * Bv[s]);
            y = fmaf(h[s], Cv[s], y);
        }
        y = fmaf(uv, Dc, y);
        y *= zv / (1.f + __expf(-zv));
        ybf[t * DINNER + c] = f2bf(y);
        dtv = dtn; uv = un; zv = zn;
    }
}

// ---------------------------------------------------------------------------
extern "C" void kernel_launch(void* const* d_in, const int* in_sizes, int n_in,
                              void* d_out, int out_size, void* d_ws, size_t ws_size,
                              hipStream_t stream) {
    const float* x       = (const float*)d_in[0];
    const float* rms_w   = (const float*)d_in[1];
    const float* W_in    = (const float*)d_in[2];
    const float* conv_w  = (const float*)d_in[3];
    const float* conv_b  = (const float*)d_in[4];
    const float* W_xproj = (const float*)d_in[5];
    const float* W_dt    = (const float*)d_in[6];
    const float* b_dt    = (const float*)d_in[7];
    const float* A_log   = (const float*)d_in[8];
    const float* D_param = (const float*)d_in[9];
    const float* W_out   = (const float*)d_in[10];
    float* out = (float*)d_out;

    float* ws    = (float*)d_ws;
    float*  xzb  = ws;                                   // NTOK*E2
    float*  ucb  = xzb + (size_t)NTOK * E2;              // NTOK*DINNER
    float*  xdbb = ucb + (size_t)NTOK * DINNER;          // NTOK*80
    float*  dtb  = xdbb + (size_t)NTOK * XPROJ_N;        // NTOK*DINNER
    float*  Pbuf = dtb + (size_t)NTOK * DINNER;          // B*NC*DINNER*DSTATE
    float*  Sbuf = Pbuf + (size_t)BATCH * NC * DINNER * DSTATE;
    ushort* xnb  = (ushort*)(Sbuf + (size_t)BATCH * NC * DINNER * DSTATE);
    ushort* winb = xnb + (size_t)NTOK * DMODEL;          // E2*DMODEL bf16
    ushort* woutb= winb + (size_t)E2 * DMODEL;           // DMODEL*DINNER bf16
    ushort* ybf  = woutb + (size_t)DMODEL * DINNER;      // NTOK*DINNER bf16

    rmsnorm_bf16_kernel<<<NTOK / 4, 256, 0, stream>>>(x, rms_w, xnb);
    f32_to_bf16_kernel<<<(E2 * DMODEL / 4 + 255) / 256, 256, 0, stream>>>(
        W_in, winb, E2 * DMODEL / 4);
    f32_to_bf16_kernel<<<(DMODEL * DINNER / 4 + 255) / 256, 256, 0, stream>>>(
        W_out, woutb, DMODEL * DINNER / 4);

    gemm_bf16<E2, DMODEL, false>
        <<<dim3(E2 / 128, NTOK / 128), 256, 0, stream>>>(xnb, winb, xzb, nullptr);

    conv_silu_kernel<<<(NTOK * DINNER) / 256, 256, 0, stream>>>(
        xzb, conv_w, conv_b, ucb);

    xproj_dt_kernel<<<NTOK, 256, 0, stream>>>(
        ucb, W_xproj, W_dt, b_dt, xdbb, dtb);

    scan_pass1<<<dim3(DINNER / 256, NC - 1, BATCH), 256, 0, stream>>>(
        dtb, ucb, xdbb, A_log, Pbuf, Sbuf);

    scan_pass2<<<dim3(DINNER / 256, NC, BATCH), 256, 0, stream>>>(
        dtb, ucb, xzb, xdbb, A_log, D_param, Pbuf, Sbuf, ybf);

    gemm_bf16<DMODEL, DINNER, true>
        <<<dim3(DMODEL / 128, NTOK / 128), 256, 0, stream>>>(ybf, woutb, out, x);
}

// Round 4
// 269.051 us; speedup vs baseline: 5.4743x; 1.5124x over previous
//
#include <hip/hip_runtime.h>
#include <hip/hip_bf16.h>
#include <math.h>

// Problem constants
#define BATCH 4
#define SEQ   1024
#define NTOK  4096          // BATCH*SEQ
#define DMODEL 768
#define DINNER 1536
#define E2     3072         // 2*DINNER
#define DTRANK 48
#define DSTATE 16
#define NC 16               // time chunks for the scan
#define CL (SEQ / NC)       // 64 steps per chunk

typedef __attribute__((ext_vector_type(8))) short bf16x8;
typedef __attribute__((ext_vector_type(4))) float f32x4;

__device__ __forceinline__ ushort f2bf(float f) {
    union { float f; unsigned u; } v; v.f = f;
    unsigned r = (v.u + 0x7FFF + ((v.u >> 16) & 1)) >> 16;   // RNE
    return (ushort)r;
}

// ---------------------------------------------------------------------------
// Kernel 1: fused RMSNorm -> bf16 xn.  One wave per token.
__global__ __launch_bounds__(256) void rmsnorm_bf16_kernel(
    const float* __restrict__ x, const float* __restrict__ rms_w,
    ushort* __restrict__ xnb) {
    int t    = blockIdx.x * 4 + (threadIdx.x >> 6);
    int lane = threadIdx.x & 63;
    const float4* xp = (const float4*)(x + (size_t)t * DMODEL);
    const float4* wp = (const float4*)rms_w;
    float4 v[3];
    float ss = 0.f;
#pragma unroll
    for (int i = 0; i < 3; ++i) {
        v[i] = xp[lane + 64 * i];
        ss += v[i].x * v[i].x + v[i].y * v[i].y + v[i].z * v[i].z + v[i].w * v[i].w;
    }
#pragma unroll
    for (int m = 32; m >= 1; m >>= 1) ss += __shfl_xor(ss, m, 64);
    float r = rsqrtf(ss * (1.f / DMODEL) + 1e-5f);
#pragma unroll
    for (int i = 0; i < 3; ++i) {
        float4 wv = wp[lane + 64 * i];
        ushort4 o = make_ushort4(f2bf(v[i].x * wv.x * r), f2bf(v[i].y * wv.y * r),
                                 f2bf(v[i].z * wv.z * r), f2bf(v[i].w * wv.w * r));
        *(ushort4*)(xnb + (size_t)t * DMODEL + (size_t)(lane + 64 * i) * 4) = o;
    }
}

// ---------------------------------------------------------------------------
// fp32 -> bf16 elementwise convert (for weights), float4 granularity.
__global__ __launch_bounds__(256) void f32_to_bf16_kernel(
    const float* __restrict__ in, ushort* __restrict__ out, int n4) {
    int i = blockIdx.x * 256 + threadIdx.x;
    if (i < n4) {
        float4 v = ((const float4*)in)[i];
        ((ushort4*)out)[i] = make_ushort4(f2bf(v.x), f2bf(v.y), f2bf(v.z), f2bf(v.w));
    }
}

// W_xproj [80][1536] -> bf16 [128][1536], rows 80..127 zero.
__global__ __launch_bounds__(256) void wxp_pad_kernel(
    const float* __restrict__ in, ushort* __restrict__ out) {
    int i = blockIdx.x * 256 + threadIdx.x;        // over 128*384
    int row = i / 384, col4 = i % 384;
    ushort4 o = make_ushort4(0, 0, 0, 0);
    if (row < 80) {
        float4 v = ((const float4*)(in + (size_t)row * DINNER))[col4];
        o = make_ushort4(f2bf(v.x), f2bf(v.y), f2bf(v.z), f2bf(v.w));
    }
    ((ushort4*)(out + (size_t)row * DINNER))[col4] = o;
}

// W_dt [1536][48] -> bf16 [1536][64], cols 48..63 zero.
__global__ __launch_bounds__(256) void wdt_pad_kernel(
    const float* __restrict__ in, ushort* __restrict__ out) {
    int i = blockIdx.x * 256 + threadIdx.x;        // over 1536*16
    int row = i / 16, col4 = i % 16;
    ushort4 o = make_ushort4(0, 0, 0, 0);
    if (col4 < 12) {
        float4 v = *(const float4*)(in + (size_t)row * DTRANK + col4 * 4);
        o = make_ushort4(f2bf(v.x), f2bf(v.y), f2bf(v.z), f2bf(v.w));
    }
    ((ushort4*)(out + (size_t)row * 64))[col4] = o;
}

// ---------------------------------------------------------------------------
// bf16 MFMA GEMM (m97 structure): C[M,N] = A[M,K] * B[N,K]^T
// EPI: 0 = plain fp32 store, 1 = + resid (aux), 2 = softplus(acc + aux[col]).
template<int N, int K, int EPI>
__global__ __launch_bounds__(256) void gemm_bf16(
    const ushort* __restrict__ A, const ushort* __restrict__ B,
    float* __restrict__ C, const float* __restrict__ aux) {
    __shared__ ushort As[128 * 32];
    __shared__ ushort Bs[128 * 32];
    const int tid  = threadIdx.x;
    const int w    = tid >> 6, lane = tid & 63;
    const int row0 = blockIdx.y * 128, col0 = blockIdx.x * 128;
    const int wr   = (w >> 1) * 64, wc = (w & 1) * 64;

    f32x4 acc[4][4];
#pragma unroll
    for (int mi = 0; mi < 4; ++mi)
#pragma unroll
        for (int ni = 0; ni < 4; ++ni)
            acc[mi][ni] = (f32x4){0.f, 0.f, 0.f, 0.f};

    const int ci0 = w * 64 + lane;
    const int ci1 = 256 + w * 64 + lane;
    const ushort* ga0 = A + (size_t)(row0 + (ci0 >> 2)) * K + (ci0 & 3) * 8;
    const ushort* ga1 = A + (size_t)(row0 + (ci1 >> 2)) * K + (ci1 & 3) * 8;
    const ushort* gb0 = B + (size_t)(col0 + (ci0 >> 2)) * K + (ci0 & 3) * 8;
    const ushort* gb1 = B + (size_t)(col0 + (ci1 >> 2)) * K + (ci1 & 3) * 8;
    ushort* lda0 = As + w * 512;
    ushort* lda1 = As + 2048 + w * 512;
    ushort* ldb0 = Bs + w * 512;
    ushort* ldb1 = Bs + 2048 + w * 512;

    const int fra = (lane & 15) * 32 + (lane >> 4) * 8;

    for (int k0 = 0; k0 < K; k0 += 32) {
        __builtin_amdgcn_global_load_lds(
            (const __attribute__((address_space(1))) void*)(ga0 + k0),
            (__attribute__((address_space(3))) void*)lda0, 16, 0, 0);
        __builtin_amdgcn_global_load_lds(
            (const __attribute__((address_space(1))) void*)(ga1 + k0),
            (__attribute__((address_space(3))) void*)lda1, 16, 0, 0);
        __builtin_amdgcn_global_load_lds(
            (const __attribute__((address_space(1))) void*)(gb0 + k0),
            (__attribute__((address_space(3))) void*)ldb0, 16, 0, 0);
        __builtin_amdgcn_global_load_lds(
            (const __attribute__((address_space(1))) void*)(gb1 + k0),
            (__attribute__((address_space(3))) void*)ldb1, 16, 0, 0);
        __syncthreads();

        bf16x8 af[4], bfr[4];
#pragma unroll
        for (int mi = 0; mi < 4; ++mi)
            af[mi] = *(const bf16x8*)&As[(wr + mi * 16) * 32 + fra];
#pragma unroll
        for (int ni = 0; ni < 4; ++ni)
            bfr[ni] = *(const bf16x8*)&Bs[(wc + ni * 16) * 32 + fra];
#pragma unroll
        for (int mi = 0; mi < 4; ++mi)
#pragma unroll
            for (int ni = 0; ni < 4; ++ni)
                acc[mi][ni] = __builtin_amdgcn_mfma_f32_16x16x32_bf16(
                    af[mi], bfr[ni], acc[mi][ni], 0, 0, 0);
        __syncthreads();
    }

    // C/D layout: col = lane&15, row = (lane>>4)*4 + j
#pragma unroll
    for (int mi = 0; mi < 4; ++mi)
#pragma unroll
        for (int j = 0; j < 4; ++j) {
            int row = row0 + wr + mi * 16 + (lane >> 4) * 4 + j;
            int cbase = col0 + wc + (lane & 15);
            float* cp = C + (size_t)row * N + cbase;
#pragma unroll
            for (int ni = 0; ni < 4; ++ni) {
                float vv = acc[mi][ni][j];
                if (EPI == 1) vv += aux[(size_t)row * N + cbase + ni * 16];
                if (EPI == 2) {
                    float s = vv + aux[cbase + ni * 16];
                    vv = (s > 20.f) ? s : log1pf(__expf(s));
                }
                cp[ni * 16] = vv;
            }
        }
}

// ---------------------------------------------------------------------------
// x_proj GEMM: bc[4096][32] (fp32 B,C) + dtlow[4096][64] bf16 (cols 48..63 = 0)
// A = uc bf16 [4096][1536]; Bw = padded W_xproj bf16 [128][1536].
// 64-row tiles, 4 waves split M (16 rows each), 5 ni fragments (80 cols).
__global__ __launch_bounds__(256) void xproj_gemm(
    const ushort* __restrict__ A, const ushort* __restrict__ Bw,
    float* __restrict__ bc, ushort* __restrict__ dtlow) {
    __shared__ ushort As[64 * 32];
    __shared__ ushort Bs[128 * 32];
    const int tid = threadIdx.x;
    const int w = tid >> 6, lane = tid & 63;
    const int row0 = blockIdx.x * 64;

    const int ci = w * 64 + lane;                 // A tile: 1 chunk
    const ushort* ga = A + (size_t)(row0 + (ci >> 2)) * DINNER + (ci & 3) * 8;
    ushort* lda = As + w * 512;
    const int bi1 = 256 + ci;                     // B tile: 2 chunks
    const ushort* gb0 = Bw + (size_t)(ci >> 2) * DINNER + (ci & 3) * 8;
    const ushort* gb1 = Bw + (size_t)(bi1 >> 2) * DINNER + (bi1 & 3) * 8;
    ushort* ldb0 = Bs + w * 512;
    ushort* ldb1 = Bs + 2048 + w * 512;

    f32x4 acc[5];
#pragma unroll
    for (int ni = 0; ni < 5; ++ni) acc[ni] = (f32x4){0.f, 0.f, 0.f, 0.f};
    const int fra = (lane & 15) * 32 + (lane >> 4) * 8;
    const int wr = w * 16;

    for (int k0 = 0; k0 < DINNER; k0 += 32) {
        __builtin_amdgcn_global_load_lds(
            (const __attribute__((address_space(1))) void*)(ga + k0),
            (__attribute__((address_space(3))) void*)lda, 16, 0, 0);
        __builtin_amdgcn_global_load_lds(
            (const __attribute__((address_space(1))) void*)(gb0 + k0),
            (__attribute__((address_space(3))) void*)ldb0, 16, 0, 0);
        __builtin_amdgcn_global_load_lds(
            (const __attribute__((address_space(1))) void*)(gb1 + k0),
            (__attribute__((address_space(3))) void*)ldb1, 16, 0, 0);
        __syncthreads();
        bf16x8 af = *(const bf16x8*)&As[wr * 32 + fra];
#pragma unroll
        for (int ni = 0; ni < 5; ++ni) {
            bf16x8 bf = *(const bf16x8*)&Bs[(ni * 16) * 32 + fra];
            acc[ni] = __builtin_amdgcn_mfma_f32_16x16x32_bf16(af, bf, acc[ni], 0, 0, 0);
        }
        __syncthreads();
    }

    const int c15 = lane & 15;
#pragma unroll
    for (int j = 0; j < 4; ++j) {
        int row = row0 + wr + (lane >> 4) * 4 + j;
        ushort* dl = dtlow + (size_t)row * 64;
#pragma unroll
        for (int ni = 0; ni < 3; ++ni)
            dl[ni * 16 + c15] = f2bf(acc[ni][j]);
        dl[48 + c15] = 0;
        bc[(size_t)row * 32 + c15]      = acc[3][j];
        bc[(size_t)row * 32 + 16 + c15] = acc[4][j];
    }
}

// ---------------------------------------------------------------------------
// Kernel 3: causal depthwise conv (d_conv=4) + SiLU -> fp32 uc + bf16 uc.
__global__ __launch_bounds__(256) void conv_silu_kernel(
    const float* __restrict__ xz, const float* __restrict__ conv_w,
    const float* __restrict__ conv_b, float* __restrict__ uc,
    ushort* __restrict__ ucbf) {
    int idx = blockIdx.x * 256 + threadIdx.x;      // over NTOK*DINNER
    int c = idx % DINNER;
    int t = idx / DINNER;
    int l = t & (SEQ - 1);
    float4 w = *(const float4*)(conv_w + c * 4);
    float a = conv_b[c];
    const float* up = xz + (size_t)t * E2 + c;
    if (l >= 3) a = fmaf(up[-3 * E2], w.x, a);
    if (l >= 2) a = fmaf(up[-2 * E2], w.y, a);
    if (l >= 1) a = fmaf(up[-1 * E2], w.z, a);
    a = fmaf(up[0], w.w, a);
    float s = a / (1.f + __expf(-a));              // silu
    uc[(size_t)t * DINNER + c] = s;
    ucbf[(size_t)t * DINNER + c] = f2bf(s);
}

// ---------------------------------------------------------------------------
// Selective scan, chunked two-pass.  Thread-per-channel, h[16] in registers.
__global__ __launch_bounds__(256) void scan_pass1(
    const float* __restrict__ dtb, const float* __restrict__ ucb,
    const float* __restrict__ bcbuf, const float* __restrict__ A_log,
    float* __restrict__ Pbuf, float* __restrict__ Sbuf) {
    const int b = blockIdx.z, k = blockIdx.y, cb = blockIdx.x;
    const int tid = threadIdx.x;
    const int c = cb * 256 + tid;
    const int t0 = b * SEQ + k * CL;
    __shared__ float sB[CL][DSTATE];
    for (int i = tid; i < CL * DSTATE; i += 256) {
        int l = i >> 4, s = i & 15;
        sB[l][s] = bcbuf[(size_t)(t0 + l) * 32 + s];
    }
    __syncthreads();
    float Acs[DSTATE], h[DSTATE], P[DSTATE];
    const float4* al = (const float4*)(A_log + (size_t)c * DSTATE);
#pragma unroll
    for (int r = 0; r < 4; ++r) {
        float4 v = al[r];
        Acs[4*r+0] = -__expf(v.x); Acs[4*r+1] = -__expf(v.y);
        Acs[4*r+2] = -__expf(v.z); Acs[4*r+3] = -__expf(v.w);
    }
#pragma unroll
    for (int s = 0; s < DSTATE; ++s) { h[s] = 0.f; P[s] = 1.f; }

    size_t t = (size_t)t0;
    for (int l = 0; l < CL; ++l, ++t) {
        float dtv = dtb[t * DINNER + c];
        float uv  = ucb[t * DINNER + c];
        float Bv[DSTATE];
        *(float4*)&Bv[0]  = *(const float4*)&sB[l][0];
        *(float4*)&Bv[4]  = *(const float4*)&sB[l][4];
        *(float4*)&Bv[8]  = *(const float4*)&sB[l][8];
        *(float4*)&Bv[12] = *(const float4*)&sB[l][12];
        float dtu = dtv * uv;
#pragma unroll
        for (int s = 0; s < DSTATE; ++s) {
            float dA = __expf(dtv * Acs[s]);
            h[s] = fmaf(dA, h[s], dtu * Bv[s]);
            P[s] *= dA;
        }
    }
    size_t base = ((size_t)(b * NC + k) * DINNER + c) * DSTATE;
    float4* Pp = (float4*)(Pbuf + base);
    float4* Sp = (float4*)(Sbuf + base);
#pragma unroll
    for (int r = 0; r < 4; ++r) {
        Pp[r] = make_float4(P[4*r], P[4*r+1], P[4*r+2], P[4*r+3]);
        Sp[r] = make_float4(h[4*r], h[4*r+1], h[4*r+2], h[4*r+3]);
    }
}

// Pass 2: combine prior chunk summaries in-register, replay chunk, emit gated y
// directly in bf16 (GEMM3's A operand).
__global__ __launch_bounds__(256) void scan_pass2(
    const float* __restrict__ dtb, const float* __restrict__ ucb,
    const float* __restrict__ xz, const float* __restrict__ bcbuf,
    const float* __restrict__ A_log, const float* __restrict__ D_param,
    const float* __restrict__ Pbuf, const float* __restrict__ Sbuf,
    ushort* __restrict__ ybf) {
    const int b = blockIdx.z, k = blockIdx.y, cb = blockIdx.x;
    const int tid = threadIdx.x;
    const int c = cb * 256 + tid;
    const int t0 = b * SEQ + k * CL;
    __shared__ float sBC[CL][2 * DSTATE];
    for (int i = tid; i < CL * 2 * DSTATE; i += 256) {
        int l = i >> 5, j = i & 31;
        sBC[l][j] = bcbuf[(size_t)(t0 + l) * 32 + j];
    }
    __syncthreads();
    float Acs[DSTATE], h[DSTATE];
    const float4* al = (const float4*)(A_log + (size_t)c * DSTATE);
#pragma unroll
    for (int r = 0; r < 4; ++r) {
        float4 v = al[r];
        Acs[4*r+0] = -__expf(v.x); Acs[4*r+1] = -__expf(v.y);
        Acs[4*r+2] = -__expf(v.z); Acs[4*r+3] = -__expf(v.w);
    }
#pragma unroll
    for (int s = 0; s < DSTATE; ++s) h[s] = 0.f;
    for (int kk = 0; kk < k; ++kk) {
        size_t sb = ((size_t)(b * NC + kk) * DINNER + c) * DSTATE;
        const float4* Pp = (const float4*)(Pbuf + sb);
        const float4* Sp = (const float4*)(Sbuf + sb);
#pragma unroll
        for (int r = 0; r < 4; ++r) {
            float4 P4 = Pp[r]; float4 S4 = Sp[r];
            h[4*r+0] = fmaf(P4.x, h[4*r+0], S4.x);
            h[4*r+1] = fmaf(P4.y, h[4*r+1], S4.y);
            h[4*r+2] = fmaf(P4.z, h[4*r+2], S4.z);
            h[4*r+3] = fmaf(P4.w, h[4*r+3], S4.w);
        }
    }
    const float Dc = D_param[c];
    size_t t = (size_t)t0;
    float dtv = dtb[t * DINNER + c];
    float uv  = ucb[t * DINNER + c];
    float zv  = xz[t * E2 + DINNER + c];
    for (int l = 0; l < CL; ++l, ++t) {
        float dtn = 0.f, un = 0.f, zn = 0.f;
        if (l + 1 < CL) {                       // prefetch next step
            dtn = dtb[(t + 1) * DINNER + c];
            un  = ucb[(t + 1) * DINNER + c];
            zn  = xz[(t + 1) * E2 + DINNER + c];
        }
        float Bv[DSTATE], Cv[DSTATE];
        *(float4*)&Bv[0]  = *(const float4*)&sBC[l][0];
        *(float4*)&Bv[4]  = *(const float4*)&sBC[l][4];
        *(float4*)&Bv[8]  = *(const float4*)&sBC[l][8];
        *(float4*)&Bv[12] = *(const float4*)&sBC[l][12];
        *(float4*)&Cv[0]  = *(const float4*)&sBC[l][16];
        *(float4*)&Cv[4]  = *(const float4*)&sBC[l][20];
        *(float4*)&Cv[8]  = *(const float4*)&sBC[l][24];
        *(float4*)&Cv[12] = *(const float4*)&sBC[l][28];
        float dtu = dtv * uv;
        float y = 0.f;
#pragma unroll
        for (int s = 0; s < DSTATE; ++s) {
            float dA = __expf(dtv * Acs[s]);
            h[s] = fmaf(dA, h[s], dtu * Bv[s]);
            y = fmaf(h[s], Cv[s], y);
        }
        y = fmaf(uv, Dc, y);
        y *= zv / (1.f + __expf(-zv));
        ybf[t * DINNER + c] = f2bf(y);
        dtv = dtn; uv = un; zv = zn;
    }
}

// ---------------------------------------------------------------------------
extern "C" void kernel_launch(void* const* d_in, const int* in_sizes, int n_in,
                              void* d_out, int out_size, void* d_ws, size_t ws_size,
                              hipStream_t stream) {
    const float* x       = (const float*)d_in[0];
    const float* rms_w   = (const float*)d_in[1];
    const float* W_in    = (const float*)d_in[2];
    const float* conv_w  = (const float*)d_in[3];
    const float* conv_b  = (const float*)d_in[4];
    const float* W_xproj = (const float*)d_in[5];
    const float* W_dt    = (const float*)d_in[6];
    const float* b_dt    = (const float*)d_in[7];
    const float* A_log   = (const float*)d_in[8];
    const float* D_param = (const float*)d_in[9];
    const float* W_out   = (const float*)d_in[10];
    float* out = (float*)d_out;

    float* ws    = (float*)d_ws;
    float*  xzb  = ws;                                   // NTOK*E2
    float*  ucb  = xzb + (size_t)NTOK * E2;              // NTOK*DINNER
    float*  bcb  = ucb + (size_t)NTOK * DINNER;          // NTOK*32
    float*  dtb  = bcb + (size_t)NTOK * 32;              // NTOK*DINNER
    float*  Pbuf = dtb + (size_t)NTOK * DINNER;          // B*NC*DINNER*DSTATE
    float*  Sbuf = Pbuf + (size_t)BATCH * NC * DINNER * DSTATE;
    ushort* xnb  = (ushort*)(Sbuf + (size_t)BATCH * NC * DINNER * DSTATE);
    ushort* winb = xnb + (size_t)NTOK * DMODEL;          // E2*DMODEL
    ushort* woutb= winb + (size_t)E2 * DMODEL;           // DMODEL*DINNER
    ushort* ybf  = woutb + (size_t)DMODEL * DINNER;      // NTOK*DINNER
    ushort* ucbf = ybf + (size_t)NTOK * DINNER;          // NTOK*DINNER
    ushort* wxpb = ucbf + (size_t)NTOK * DINNER;         // 128*DINNER
    ushort* wdtb = wxpb + (size_t)128 * DINNER;          // DINNER*64
    ushort* dtlb = wdtb + (size_t)DINNER * 64;           // NTOK*64

    rmsnorm_bf16_kernel<<<NTOK / 4, 256, 0, stream>>>(x, rms_w, xnb);
    f32_to_bf16_kernel<<<(E2 * DMODEL / 4 + 255) / 256, 256, 0, stream>>>(
        W_in, winb, E2 * DMODEL / 4);
    f32_to_bf16_kernel<<<(DMODEL * DINNER / 4 + 255) / 256, 256, 0, stream>>>(
        W_out, woutb, DMODEL * DINNER / 4);
    wxp_pad_kernel<<<(128 * 384) / 256, 256, 0, stream>>>(W_xproj, wxpb);
    wdt_pad_kernel<<<(1536 * 16) / 256, 256, 0, stream>>>(W_dt, wdtb);

    gemm_bf16<E2, DMODEL, 0>
        <<<dim3(E2 / 128, NTOK / 128), 256, 0, stream>>>(xnb, winb, xzb, nullptr);

    conv_silu_kernel<<<(NTOK * DINNER) / 256, 256, 0, stream>>>(
        xzb, conv_w, conv_b, ucb, ucbf);

    xproj_gemm<<<NTOK / 64, 256, 0, stream>>>(ucbf, wxpb, bcb, dtlb);

    gemm_bf16<DINNER, 64, 2>
        <<<dim3(DINNER / 128, NTOK / 128), 256, 0, stream>>>(dtlb, wdtb, dtb, b_dt);

    scan_pass1<<<dim3(DINNER / 256, NC - 1, BATCH), 256, 0, stream>>>(
        dtb, ucb, bcb, A_log, Pbuf, Sbuf);

    scan_pass2<<<dim3(DINNER / 256, NC, BATCH), 256, 0, stream>>>(
        dtb, ucb, xzb, bcb, A_log, D_param, Pbuf, Sbuf, ybf);

    gemm_bf16<DMODEL, DINNER, 1>
        <<<dim3(DMODEL / 128, NTOK / 128), 256, 0, stream>>>(ybf, woutb, out, x);
}

// Round 5
// 221.348 us; speedup vs baseline: 6.6540x; 1.2155x over previous
//
#include <hip/hip_runtime.h>
#include <hip/hip_bf16.h>
#include <math.h>

// Problem constants
#define BATCH 4
#define SEQ   1024
#define NTOK  4096          // BATCH*SEQ
#define DMODEL 768
#define DINNER 1536
#define E2     3072         // 2*DINNER
#define DTRANK 48
#define DSTATE 16
#define NC 32               // time chunks for the scan
#define CL (SEQ / NC)       // 32 steps per chunk
#define KSPLIT 4            // xproj split-K
#define KSEG (DINNER / KSPLIT)

typedef __attribute__((ext_vector_type(8))) short bf16x8;
typedef __attribute__((ext_vector_type(4))) float f32x4;

__device__ __forceinline__ ushort f2bf(float f) {
    union { float f; unsigned u; } v; v.f = f;
    unsigned r = (v.u + 0x7FFF + ((v.u >> 16) & 1)) >> 16;   // RNE
    return (ushort)r;
}
__device__ __forceinline__ float bf2f(ushort u) {
    union { unsigned u; float f; } v; v.u = ((unsigned)u) << 16;
    return v.f;
}

// ---------------------------------------------------------------------------
// Kernel 1: fused RMSNorm -> bf16 xn.  One wave per token.
__global__ __launch_bounds__(256) void rmsnorm_bf16_kernel(
    const float* __restrict__ x, const float* __restrict__ rms_w,
    ushort* __restrict__ xnb) {
    int t    = blockIdx.x * 4 + (threadIdx.x >> 6);
    int lane = threadIdx.x & 63;
    const float4* xp = (const float4*)(x + (size_t)t * DMODEL);
    const float4* wp = (const float4*)rms_w;
    float4 v[3];
    float ss = 0.f;
#pragma unroll
    for (int i = 0; i < 3; ++i) {
        v[i] = xp[lane + 64 * i];
        ss += v[i].x * v[i].x + v[i].y * v[i].y + v[i].z * v[i].z + v[i].w * v[i].w;
    }
#pragma unroll
    for (int m = 32; m >= 1; m >>= 1) ss += __shfl_xor(ss, m, 64);
    float r = rsqrtf(ss * (1.f / DMODEL) + 1e-5f);
#pragma unroll
    for (int i = 0; i < 3; ++i) {
        float4 wv = wp[lane + 64 * i];
        ushort4 o = make_ushort4(f2bf(v[i].x * wv.x * r), f2bf(v[i].y * wv.y * r),
                                 f2bf(v[i].z * wv.z * r), f2bf(v[i].w * wv.w * r));
        *(ushort4*)(xnb + (size_t)t * DMODEL + (size_t)(lane + 64 * i) * 4) = o;
    }
}

// ---------------------------------------------------------------------------
// fp32 -> bf16 elementwise convert (for weights), float4 granularity.
__global__ __launch_bounds__(256) void f32_to_bf16_kernel(
    const float* __restrict__ in, ushort* __restrict__ out, int n4) {
    int i = blockIdx.x * 256 + threadIdx.x;
    if (i < n4) {
        float4 v = ((const float4*)in)[i];
        ((ushort4*)out)[i] = make_ushort4(f2bf(v.x), f2bf(v.y), f2bf(v.z), f2bf(v.w));
    }
}

// W_xproj [80][1536] -> bf16 [128][1536], rows 80..127 zero.
__global__ __launch_bounds__(256) void wxp_pad_kernel(
    const float* __restrict__ in, ushort* __restrict__ out) {
    int i = blockIdx.x * 256 + threadIdx.x;        // over 128*384
    int row = i / 384, col4 = i % 384;
    ushort4 o = make_ushort4(0, 0, 0, 0);
    if (row < 80) {
        float4 v = ((const float4*)(in + (size_t)row * DINNER))[col4];
        o = make_ushort4(f2bf(v.x), f2bf(v.y), f2bf(v.z), f2bf(v.w));
    }
    ((ushort4*)(out + (size_t)row * DINNER))[col4] = o;
}

// W_dt [1536][48] -> bf16 [1536][64], cols 48..63 zero.
__global__ __launch_bounds__(256) void wdt_pad_kernel(
    const float* __restrict__ in, ushort* __restrict__ out) {
    int i = blockIdx.x * 256 + threadIdx.x;        // over 1536*16
    int row = i / 16, col4 = i % 16;
    ushort4 o = make_ushort4(0, 0, 0, 0);
    if (col4 < 12) {
        float4 v = *(const float4*)(in + (size_t)row * DTRANK + col4 * 4);
        o = make_ushort4(f2bf(v.x), f2bf(v.y), f2bf(v.z), f2bf(v.w));
    }
    ((ushort4*)(out + (size_t)row * 64))[col4] = o;
}

// ---------------------------------------------------------------------------
// bf16 MFMA GEMM (m97 structure): C[M,N] = A[M,K] * B[N,K]^T
// EPI: 0 = fp32 store, 1 = fp32 + resid(aux), 2 = bf16 softplus(acc+aux[col]),
//      3 = bf16 store.
template<int N, int K, int EPI>
__global__ __launch_bounds__(256) void gemm_bf16(
    const ushort* __restrict__ A, const ushort* __restrict__ B,
    void* __restrict__ Cout, const float* __restrict__ aux) {
    __shared__ ushort As[128 * 32];
    __shared__ ushort Bs[128 * 32];
    const int tid  = threadIdx.x;
    const int w    = tid >> 6, lane = tid & 63;
    const int row0 = blockIdx.y * 128, col0 = blockIdx.x * 128;
    const int wr   = (w >> 1) * 64, wc = (w & 1) * 64;

    f32x4 acc[4][4];
#pragma unroll
    for (int mi = 0; mi < 4; ++mi)
#pragma unroll
        for (int ni = 0; ni < 4; ++ni)
            acc[mi][ni] = (f32x4){0.f, 0.f, 0.f, 0.f};

    const int ci0 = w * 64 + lane;
    const int ci1 = 256 + w * 64 + lane;
    const ushort* ga0 = A + (size_t)(row0 + (ci0 >> 2)) * K + (ci0 & 3) * 8;
    const ushort* ga1 = A + (size_t)(row0 + (ci1 >> 2)) * K + (ci1 & 3) * 8;
    const ushort* gb0 = B + (size_t)(col0 + (ci0 >> 2)) * K + (ci0 & 3) * 8;
    const ushort* gb1 = B + (size_t)(col0 + (ci1 >> 2)) * K + (ci1 & 3) * 8;
    ushort* lda0 = As + w * 512;
    ushort* lda1 = As + 2048 + w * 512;
    ushort* ldb0 = Bs + w * 512;
    ushort* ldb1 = Bs + 2048 + w * 512;

    const int fra = (lane & 15) * 32 + (lane >> 4) * 8;

    for (int k0 = 0; k0 < K; k0 += 32) {
        __builtin_amdgcn_global_load_lds(
            (const __attribute__((address_space(1))) void*)(ga0 + k0),
            (__attribute__((address_space(3))) void*)lda0, 16, 0, 0);
        __builtin_amdgcn_global_load_lds(
            (const __attribute__((address_space(1))) void*)(ga1 + k0),
            (__attribute__((address_space(3))) void*)lda1, 16, 0, 0);
        __builtin_amdgcn_global_load_lds(
            (const __attribute__((address_space(1))) void*)(gb0 + k0),
            (__attribute__((address_space(3))) void*)ldb0, 16, 0, 0);
        __builtin_amdgcn_global_load_lds(
            (const __attribute__((address_space(1))) void*)(gb1 + k0),
            (__attribute__((address_space(3))) void*)ldb1, 16, 0, 0);
        __syncthreads();

        bf16x8 af[4], bfr[4];
#pragma unroll
        for (int mi = 0; mi < 4; ++mi)
            af[mi] = *(const bf16x8*)&As[(wr + mi * 16) * 32 + fra];
#pragma unroll
        for (int ni = 0; ni < 4; ++ni)
            bfr[ni] = *(const bf16x8*)&Bs[(wc + ni * 16) * 32 + fra];
#pragma unroll
        for (int mi = 0; mi < 4; ++mi)
#pragma unroll
            for (int ni = 0; ni < 4; ++ni)
                acc[mi][ni] = __builtin_amdgcn_mfma_f32_16x16x32_bf16(
                    af[mi], bfr[ni], acc[mi][ni], 0, 0, 0);
        __syncthreads();
    }

    // C/D layout: col = lane&15, row = (lane>>4)*4 + j
#pragma unroll
    for (int mi = 0; mi < 4; ++mi)
#pragma unroll
        for (int j = 0; j < 4; ++j) {
            int row = row0 + wr + mi * 16 + (lane >> 4) * 4 + j;
            int cbase = col0 + wc + (lane & 15);
#pragma unroll
            for (int ni = 0; ni < 4; ++ni) {
                float vv = acc[mi][ni][j];
                int col = cbase + ni * 16;
                if (EPI == 0)
                    ((float*)Cout)[(size_t)row * N + col] = vv;
                if (EPI == 1)
                    ((float*)Cout)[(size_t)row * N + col] =
                        vv + aux[(size_t)row * N + col];
                if (EPI == 2) {
                    float s = vv + aux[col];
                    float sp = (s > 20.f) ? s : log1pf(__expf(s));
                    ((ushort*)Cout)[(size_t)row * N + col] = f2bf(sp);
                }
                if (EPI == 3)
                    ((ushort*)Cout)[(size_t)row * N + col] = f2bf(vv);
            }
        }
}

// ---------------------------------------------------------------------------
// x_proj split-K GEMM: partial[ks][4096][80] fp32.
// A = uc bf16 [4096][1536]; Bw = padded W_xproj bf16 [128][1536].
__global__ __launch_bounds__(256) void xproj_gemm_sk(
    const ushort* __restrict__ A, const ushort* __restrict__ Bw,
    float* __restrict__ part) {
    __shared__ ushort As[64 * 32];
    __shared__ ushort Bs[128 * 32];
    const int tid = threadIdx.x;
    const int w = tid >> 6, lane = tid & 63;
    const int row0 = blockIdx.x * 64;
    const int kbase = blockIdx.y * KSEG;

    const int ci = w * 64 + lane;
    const ushort* ga = A + (size_t)(row0 + (ci >> 2)) * DINNER + kbase + (ci & 3) * 8;
    ushort* lda = As + w * 512;
    const int bi1 = 256 + ci;
    const ushort* gb0 = Bw + (size_t)(ci >> 2) * DINNER + kbase + (ci & 3) * 8;
    const ushort* gb1 = Bw + (size_t)(bi1 >> 2) * DINNER + kbase + (bi1 & 3) * 8;
    ushort* ldb0 = Bs + w * 512;
    ushort* ldb1 = Bs + 2048 + w * 512;

    f32x4 acc[5];
#pragma unroll
    for (int ni = 0; ni < 5; ++ni) acc[ni] = (f32x4){0.f, 0.f, 0.f, 0.f};
    const int fra = (lane & 15) * 32 + (lane >> 4) * 8;
    const int wr = w * 16;

    for (int k0 = 0; k0 < KSEG; k0 += 32) {
        __builtin_amdgcn_global_load_lds(
            (const __attribute__((address_space(1))) void*)(ga + k0),
            (__attribute__((address_space(3))) void*)lda, 16, 0, 0);
        __builtin_amdgcn_global_load_lds(
            (const __attribute__((address_space(1))) void*)(gb0 + k0),
            (__attribute__((address_space(3))) void*)ldb0, 16, 0, 0);
        __builtin_amdgcn_global_load_lds(
            (const __attribute__((address_space(1))) void*)(gb1 + k0),
            (__attribute__((address_space(3))) void*)ldb1, 16, 0, 0);
        __syncthreads();
        bf16x8 af = *(const bf16x8*)&As[wr * 32 + fra];
#pragma unroll
        for (int ni = 0; ni < 5; ++ni) {
            bf16x8 bf = *(const bf16x8*)&Bs[(ni * 16) * 32 + fra];
            acc[ni] = __builtin_amdgcn_mfma_f32_16x16x32_bf16(af, bf, acc[ni], 0, 0, 0);
        }
        __syncthreads();
    }

    const int c15 = lane & 15;
    float* pp = part + (size_t)blockIdx.y * NTOK * 80;
#pragma unroll
    for (int j = 0; j < 4; ++j) {
        int row = row0 + wr + (lane >> 4) * 4 + j;
#pragma unroll
        for (int ni = 0; ni < 5; ++ni)
            pp[(size_t)row * 80 + ni * 16 + c15] = acc[ni][j];
    }
}

// Combine split-K partials -> bc fp32 [4096][32], dtlow bf16 [4096][64].
__global__ __launch_bounds__(256) void xproj_combine(
    const float* __restrict__ part, float* __restrict__ bc,
    ushort* __restrict__ dtl) {
    int idx = blockIdx.x * 256 + threadIdx.x;      // over NTOK*96
    int row = idx / 96, j = idx % 96;
    if (j >= 48 && j < 64) { dtl[(size_t)row * 64 + j] = 0; return; }
    int col = (j < 48) ? j : j - 16;
    size_t o = (size_t)row * 80 + col;
    float s = part[o] + part[o + (size_t)NTOK * 80]
            + part[o + 2 * (size_t)NTOK * 80] + part[o + 3 * (size_t)NTOK * 80];
    if (j < 48) dtl[(size_t)row * 64 + j] = f2bf(s);
    else        bc[(size_t)row * 32 + (j - 64)] = s;
}

// ---------------------------------------------------------------------------
// Kernel 3: causal depthwise conv (d_conv=4) + SiLU, bf16 in / bf16 out.
__global__ __launch_bounds__(256) void conv_silu_kernel(
    const ushort* __restrict__ xz, const float* __restrict__ conv_w,
    const float* __restrict__ conv_b, ushort* __restrict__ ucbf) {
    int idx = blockIdx.x * 256 + threadIdx.x;      // over NTOK*DINNER
    int c = idx % DINNER;
    int t = idx / DINNER;
    int l = t & (SEQ - 1);
    float4 w = *(const float4*)(conv_w + c * 4);
    float a = conv_b[c];
    const ushort* up = xz + (size_t)t * E2 + c;
    if (l >= 3) a = fmaf(bf2f(up[-3 * E2]), w.x, a);
    if (l >= 2) a = fmaf(bf2f(up[-2 * E2]), w.y, a);
    if (l >= 1) a = fmaf(bf2f(up[-1 * E2]), w.z, a);
    a = fmaf(bf2f(up[0]), w.w, a);
    float s = a / (1.f + __expf(-a));              // silu
    ucbf[(size_t)t * DINNER + c] = f2bf(s);
}

// ---------------------------------------------------------------------------
// Selective scan, chunked.  Thread-per-channel, h[16] in registers.
// Pass 1: per (b,chunk,c): P = prod(dA), S = chunk scan from 0.
__global__ __launch_bounds__(256) void scan_pass1(
    const ushort* __restrict__ dtb, const ushort* __restrict__ ucb,
    const float* __restrict__ bcbuf, const float* __restrict__ A_log,
    float* __restrict__ Pbuf, float* __restrict__ Sbuf) {
    const int b = blockIdx.z, k = blockIdx.y, cb = blockIdx.x;
    const int tid = threadIdx.x;
    const int c = cb * 256 + tid;
    const int t0 = b * SEQ + k * CL;
    __shared__ float sB[CL][DSTATE];
    for (int i = tid; i < CL * DSTATE; i += 256) {
        int l = i >> 4, s = i & 15;
        sB[l][s] = bcbuf[(size_t)(t0 + l) * 32 + s];
    }
    __syncthreads();
    float Acs[DSTATE], h[DSTATE], P[DSTATE];
    const float4* al = (const float4*)(A_log + (size_t)c * DSTATE);
#pragma unroll
    for (int r = 0; r < 4; ++r) {
        float4 v = al[r];
        Acs[4*r+0] = -__expf(v.x); Acs[4*r+1] = -__expf(v.y);
        Acs[4*r+2] = -__expf(v.z); Acs[4*r+3] = -__expf(v.w);
    }
#pragma unroll
    for (int s = 0; s < DSTATE; ++s) { h[s] = 0.f; P[s] = 1.f; }

    size_t t = (size_t)t0;
    for (int l = 0; l < CL; ++l, ++t) {
        float dtv = bf2f(dtb[t * DINNER + c]);
        float uv  = bf2f(ucb[t * DINNER + c]);
        float Bv[DSTATE];
        *(float4*)&Bv[0]  = *(const float4*)&sB[l][0];
        *(float4*)&Bv[4]  = *(const float4*)&sB[l][4];
        *(float4*)&Bv[8]  = *(const float4*)&sB[l][8];
        *(float4*)&Bv[12] = *(const float4*)&sB[l][12];
        float dtu = dtv * uv;
#pragma unroll
        for (int s = 0; s < DSTATE; ++s) {
            float dA = __expf(dtv * Acs[s]);
            h[s] = fmaf(dA, h[s], dtu * Bv[s]);
            P[s] *= dA;
        }
    }
    size_t base = ((size_t)(b * NC + k) * DINNER + c) * DSTATE;
    float4* Pp = (float4*)(Pbuf + base);
    float4* Sp = (float4*)(Sbuf + base);
#pragma unroll
    for (int r = 0; r < 4; ++r) {
        Pp[r] = make_float4(P[4*r], P[4*r+1], P[4*r+2], P[4*r+3]);
        Sp[r] = make_float4(h[4*r], h[4*r+1], h[4*r+2], h[4*r+3]);
    }
}

// Mid: serial combine of chunk summaries -> per-chunk start state H.
// Thread = (b, c, s).
__global__ __launch_bounds__(256) void scan_mid(
    const float* __restrict__ Pbuf, const float* __restrict__ Sbuf,
    float* __restrict__ Hbuf) {
    int idx = blockIdx.x * 256 + threadIdx.x;      // over BATCH*DINNER*DSTATE
    int s = idx & 15;
    int tmp = idx >> 4;
    int c = tmp % DINNER, b = tmp / DINNER;
    float h = 0.f;
    for (int k = 0; k < NC; ++k) {
        size_t off = ((size_t)(b * NC + k) * DINNER + c) * DSTATE + s;
        Hbuf[off] = h;
        if (k < NC - 1) h = fmaf(Pbuf[off], h, Sbuf[off]);
    }
}

// Pass 2: init h from H, replay chunk, emit gated y in bf16.
__global__ __launch_bounds__(256) void scan_pass2(
    const ushort* __restrict__ dtb, const ushort* __restrict__ ucb,
    const ushort* __restrict__ xz, const float* __restrict__ bcbuf,
    const float* __restrict__ A_log, const float* __restrict__ D_param,
    const float* __restrict__ Hbuf, ushort* __restrict__ ybf) {
    const int b = blockIdx.z, k = blockIdx.y, cb = blockIdx.x;
    const int tid = threadIdx.x;
    const int c = cb * 256 + tid;
    const int t0 = b * SEQ + k * CL;
    __shared__ float sBC[CL][2 * DSTATE];
    for (int i = tid; i < CL * 2 * DSTATE; i += 256) {
        int l = i >> 5, j = i & 31;
        sBC[l][j] = bcbuf[(size_t)(t0 + l) * 32 + j];
    }
    __syncthreads();
    float Acs[DSTATE], h[DSTATE];
    const float4* al = (const float4*)(A_log + (size_t)c * DSTATE);
#pragma unroll
    for (int r = 0; r < 4; ++r) {
        float4 v = al[r];
        Acs[4*r+0] = -__expf(v.x); Acs[4*r+1] = -__expf(v.y);
        Acs[4*r+2] = -__expf(v.z); Acs[4*r+3] = -__expf(v.w);
    }
    size_t hb = ((size_t)(b * NC + k) * DINNER + c) * DSTATE;
#pragma unroll
    for (int r = 0; r < 4; ++r) {
        float4 hv = *(const float4*)(Hbuf + hb + 4 * r);
        h[4*r+0] = hv.x; h[4*r+1] = hv.y; h[4*r+2] = hv.z; h[4*r+3] = hv.w;
    }
    const float Dc = D_param[c];
    size_t t = (size_t)t0;
    float dtv = bf2f(dtb[t * DINNER + c]);
    float uv  = bf2f(ucb[t * DINNER + c]);
    float zv  = bf2f(xz[t * E2 + DINNER + c]);
    for (int l = 0; l < CL; ++l, ++t) {
        float dtn = 0.f, un = 0.f, zn = 0.f;
        if (l + 1 < CL) {                       // prefetch next step
            dtn = bf2f(dtb[(t + 1) * DINNER + c]);
            un  = bf2f(ucb[(t + 1) * DINNER + c]);
            zn  = bf2f(xz[(t + 1) * E2 + DINNER + c]);
        }
        float Bv[DSTATE], Cv[DSTATE];
        *(float4*)&Bv[0]  = *(const float4*)&sBC[l][0];
        *(float4*)&Bv[4]  = *(const float4*)&sBC[l][4];
        *(float4*)&Bv[8]  = *(const float4*)&sBC[l][8];
        *(float4*)&Bv[12] = *(const float4*)&sBC[l][12];
        *(float4*)&Cv[0]  = *(const float4*)&sBC[l][16];
        *(float4*)&Cv[4]  = *(const float4*)&sBC[l][20];
        *(float4*)&Cv[8]  = *(const float4*)&sBC[l][24];
        *(float4*)&Cv[12] = *(const float4*)&sBC[l][28];
        float dtu = dtv * uv;
        float y = 0.f;
#pragma unroll
        for (int s = 0; s < DSTATE; ++s) {
            float dA = __expf(dtv * Acs[s]);
            h[s] = fmaf(dA, h[s], dtu * Bv[s]);
            y = fmaf(h[s], Cv[s], y);
        }
        y = fmaf(uv, Dc, y);
        y *= zv / (1.f + __expf(-zv));
        ybf[t * DINNER + c] = f2bf(y);
        dtv = dtn; uv = un; zv = zn;
    }
}

// ---------------------------------------------------------------------------
extern "C" void kernel_launch(void* const* d_in, const int* in_sizes, int n_in,
                              void* d_out, int out_size, void* d_ws, size_t ws_size,
                              hipStream_t stream) {
    const float* x       = (const float*)d_in[0];
    const float* rms_w   = (const float*)d_in[1];
    const float* W_in    = (const float*)d_in[2];
    const float* conv_w  = (const float*)d_in[3];
    const float* conv_b  = (const float*)d_in[4];
    const float* W_xproj = (const float*)d_in[5];
    const float* W_dt    = (const float*)d_in[6];
    const float* b_dt    = (const float*)d_in[7];
    const float* A_log   = (const float*)d_in[8];
    const float* D_param = (const float*)d_in[9];
    const float* W_out   = (const float*)d_in[10];
    float* out = (float*)d_out;

    const size_t PS = (size_t)BATCH * NC * DINNER * DSTATE;   // 3.1M floats
    float* ws    = (float*)d_ws;
    float*  bcb  = ws;                                   // NTOK*32
    float*  Pbuf = bcb + (size_t)NTOK * 32;
    float*  Sbuf = Pbuf + PS;
    float*  Hbuf = Sbuf + PS;
    float*  xpp  = Hbuf + PS;                            // KSPLIT*NTOK*80
    ushort* xnb  = (ushort*)(xpp + (size_t)KSPLIT * NTOK * 80);
    ushort* winb = xnb + (size_t)NTOK * DMODEL;          // E2*DMODEL
    ushort* woutb= winb + (size_t)E2 * DMODEL;           // DMODEL*DINNER
    ushort* wxpb = woutb + (size_t)DMODEL * DINNER;      // 128*DINNER
    ushort* wdtb = wxpb + (size_t)128 * DINNER;          // DINNER*64
    ushort* xzbf = wdtb + (size_t)DINNER * 64;           // NTOK*E2
    ushort* ucbf = xzbf + (size_t)NTOK * E2;             // NTOK*DINNER
    ushort* dtlb = ucbf + (size_t)NTOK * DINNER;         // NTOK*64
    ushort* dtbf = dtlb + (size_t)NTOK * 64;             // NTOK*DINNER
    ushort* ybf  = dtbf + (size_t)NTOK * DINNER;         // NTOK*DINNER

    rmsnorm_bf16_kernel<<<NTOK / 4, 256, 0, stream>>>(x, rms_w, xnb);
    f32_to_bf16_kernel<<<(E2 * DMODEL / 4 + 255) / 256, 256, 0, stream>>>(
        W_in, winb, E2 * DMODEL / 4);
    f32_to_bf16_kernel<<<(DMODEL * DINNER / 4 + 255) / 256, 256, 0, stream>>>(
        W_out, woutb, DMODEL * DINNER / 4);
    wxp_pad_kernel<<<(128 * 384) / 256, 256, 0, stream>>>(W_xproj, wxpb);
    wdt_pad_kernel<<<(1536 * 16) / 256, 256, 0, stream>>>(W_dt, wdtb);

    gemm_bf16<E2, DMODEL, 3>
        <<<dim3(E2 / 128, NTOK / 128), 256, 0, stream>>>(xnb, winb, xzbf, nullptr);

    conv_silu_kernel<<<(NTOK * DINNER) / 256, 256, 0, stream>>>(
        xzbf, conv_w, conv_b, ucbf);

    xproj_gemm_sk<<<dim3(NTOK / 64, KSPLIT), 256, 0, stream>>>(ucbf, wxpb, xpp);
    xproj_combine<<<(NTOK * 96) / 256, 256, 0, stream>>>(xpp, bcb, dtlb);

    gemm_bf16<DINNER, 64, 2>
        <<<dim3(DINNER / 128, NTOK / 128), 256, 0, stream>>>(dtlb, wdtb, dtbf, b_dt);

    scan_pass1<<<dim3(DINNER / 256, NC - 1, BATCH), 256, 0, stream>>>(
        dtbf, ucbf, bcb, A_log, Pbuf, Sbuf);

    scan_mid<<<(BATCH * DINNER * DSTATE) / 256, 256, 0, stream>>>(
        Pbuf, Sbuf, Hbuf);

    scan_pass2<<<dim3(DINNER / 256, NC, BATCH), 256, 0, stream>>>(
        dtbf, ucbf, xzbf, bcb, A_log, D_param, Hbuf, ybf);

    gemm_bf16<DMODEL, DINNER, 1>
        <<<dim3(DMODEL / 128, NTOK / 128), 256, 0, stream>>>(ybf, woutb, out, x);
}